// Round 1
// baseline (4748.639 us; speedup 1.0000x reference)
//
#include <hip/hip_runtime.h>
#include <math.h>

#define N_ROWS 32768
#define KCB    8192
#define DIM    512
#define BETA   0.25f

// dist-kernel tiles
#define BM 64
#define BK 128
#define BD 32

// ---------------------------------------------------------------------------
// Kernel 1: ||x||^2 per latent row and ||e||^2 per codebook row, replicating
// numpy's pairwise summation EXACTLY (128-blocks, 8 accumulators, fixed
// combine tree). fp contract OFF so each square rounds before the add, as
// numpy does (it materializes flat*flat then sums).
// ---------------------------------------------------------------------------
__global__ void sq_kernel(const float* __restrict__ lat,
                          const float* __restrict__ emb,
                          float* __restrict__ row_sq,
                          float* __restrict__ emb_sq) {
#pragma clang fp contract(off)
    int row = blockIdx.x * blockDim.x + threadIdx.x;
    const int total = N_ROWS + KCB;
    if (row >= total) return;
    const float* p = (row < N_ROWS) ? (lat + (size_t)row * DIM)
                                    : (emb + (size_t)(row - N_ROWS) * DIM);
    float B[4];
    for (int b = 0; b < 4; ++b) {
        const float* q = p + b * 128;
        float r[8];
        for (int j = 0; j < 8; ++j) { float a = q[j]; r[j] = a * a; }
        for (int i = 1; i < 16; ++i)
            for (int j = 0; j < 8; ++j) {
                float a = q[8 * i + j];
                float s = a * a;
                r[j] = r[j] + s;
            }
        B[b] = ((r[0] + r[1]) + (r[2] + r[3])) + ((r[4] + r[5]) + (r[6] + r[7]));
    }
    float s = (B[0] + B[1]) + (B[2] + B[3]);
    if (row < N_ROWS) row_sq[row] = s;
    else              emb_sq[row - N_ROWS] = s;
}

// ---------------------------------------------------------------------------
// Kernel 2: distances + argmin. Each block: BM=64 rows x all K codes,
// K-tiled by BK=128, D staged in LDS chunks of BD=32 (transposed layout so
// the 4x8 register-tile reads are ds_read_b128). dist computed with the
// same fp32 rounding chain as numpy: fl( fl(sx+se) - 2*dot ). Tie-break to
// the lowest index (numpy argmin semantics), within-thread by ascending
// scan order + strict <, across threads by (d, idx) lexicographic min.
// ---------------------------------------------------------------------------
__global__ __launch_bounds__(256) void dist_kernel(
        const float* __restrict__ lat, const float* __restrict__ emb,
        const float* __restrict__ row_sq, const float* __restrict__ emb_sq,
        int* __restrict__ enc) {
    __shared__ float xs[BD][BM];   // [32][64]  xs[d][row]
    __shared__ float es[BD][BK];   // [32][128] es[d][code]

    const int tid  = threadIdx.x;
    const int trow = tid >> 4;   // 0..15 -> rows 4*trow .. +3
    const int tcol = tid & 15;   // 0..15 -> codes 8*tcol .. +7 (per tile)
    const int row0 = blockIdx.x * BM;

    float bd[4];
    int   bi[4];
    for (int i = 0; i < 4; ++i) { bd[i] = INFINITY; bi[i] = 0; }
    float sx[4];
    for (int i = 0; i < 4; ++i) sx[i] = row_sq[row0 + 4 * trow + i];

    for (int kt = 0; kt < KCB; kt += BK) {
        float acc[4][8] = {};
        for (int d0 = 0; d0 < DIM; d0 += BD) {
            // stage x tile (64 rows x 32 d), transposed into LDS
            for (int f = tid; f < BM * BD / 4; f += 256) {
                int r = f >> 3, c4 = f & 7;
                float4 v = *(const float4*)(lat + (size_t)(row0 + r) * DIM + d0 + 4 * c4);
                xs[4 * c4 + 0][r] = v.x; xs[4 * c4 + 1][r] = v.y;
                xs[4 * c4 + 2][r] = v.z; xs[4 * c4 + 3][r] = v.w;
            }
            // stage e tile (128 codes x 32 d), transposed into LDS
            for (int f = tid; f < BK * BD / 4; f += 256) {
                int r = f >> 3, c4 = f & 7;
                float4 v = *(const float4*)(emb + (size_t)(kt + r) * DIM + d0 + 4 * c4);
                es[4 * c4 + 0][r] = v.x; es[4 * c4 + 1][r] = v.y;
                es[4 * c4 + 2][r] = v.z; es[4 * c4 + 3][r] = v.w;
            }
            __syncthreads();
            for (int dd = 0; dd < BD; ++dd) {
                float4 xv  = *(const float4*)&xs[dd][4 * trow];
                float4 ev0 = *(const float4*)&es[dd][8 * tcol];
                float4 ev1 = *(const float4*)&es[dd][8 * tcol + 4];
                float xr[4] = { xv.x, xv.y, xv.z, xv.w };
                float ec[8] = { ev0.x, ev0.y, ev0.z, ev0.w,
                                ev1.x, ev1.y, ev1.z, ev1.w };
                for (int r = 0; r < 4; ++r)
                    for (int c = 0; c < 8; ++c)
                        acc[r][c] = fmaf(xr[r], ec[c], acc[r][c]);
            }
            __syncthreads();
        }
        // epilogue for this K-tile: dist + running argmin
        for (int c = 0; c < 8; ++c) {              // ascending code order!
            int   code = kt + 8 * tcol + c;
            float se   = emb_sq[code];
            for (int r = 0; r < 4; ++r) {
                float a  = sx[r] + se;             // fl(sx+se) like numpy
                float dv = a - 2.0f * acc[r][c];   // single fp32 round
                if (dv < bd[r]) { bd[r] = dv; bi[r] = code; }
            }
        }
    }
    // reduce across the 16 lanes (same trow) holding disjoint code ranges
    for (int off = 1; off < 16; off <<= 1) {
        for (int r = 0; r < 4; ++r) {
            float od = __shfl_xor(bd[r], off);
            int   oi = __shfl_xor(bi[r], off);
            if (od < bd[r] || (od == bd[r] && oi < bi[r])) { bd[r] = od; bi[r] = oi; }
        }
    }
    if (tcol == 0)
        for (int r = 0; r < 4; ++r)
            enc[row0 + 4 * trow + r] = bi[r];
}

// ---------------------------------------------------------------------------
// Kernel 3: gather quantized rows, vq_loss with numpy-exact pairwise mean,
// index output as float, correct-count atomic. One wave per row.
// ---------------------------------------------------------------------------
__global__ void out_kernel(const float* __restrict__ lat,
                           const float* __restrict__ emb,
                           const int* __restrict__ gold,
                           const int* __restrict__ enc,
                           float* __restrict__ out,
                           int* __restrict__ counter) {
#pragma clang fp contract(off)
    const int gid  = blockIdx.x * blockDim.x + threadIdx.x;
    const int row  = gid >> 6;
    const int lane = threadIdx.x & 63;
    if (row >= N_ROWS) return;
    const int idx = enc[row];

    // quantized = emb[idx] (bit-exact gather), straight-through == quantized
    const float4* e4 = (const float4*)(emb + (size_t)idx * DIM);
    float4*       q4 = (float4*)(out + (size_t)row * DIM);
    q4[lane]      = e4[lane];
    q4[lane + 64] = e4[lane + 64];

    // vq_loss: mean((q-x)^2) with numpy pairwise tree, then m + 0.25*m
    float r = 0.0f;
    if (lane < 32) {
        const int b = lane >> 3, j = lane & 7;
        const float* ep = emb + (size_t)idx * DIM + b * 128 + j;
        const float* xp = lat + (size_t)row * DIM + b * 128 + j;
        for (int i = 0; i < 16; ++i) {
            float dq = ep[8 * i] - xp[8 * i];
            float s  = dq * dq;
            r = (i == 0) ? s : (r + s);
        }
    }
    for (int m = 1; m <= 16; m <<= 1) {
        float o = __shfl_xor(r, m);
        r = r + o;   // lane0 ends with ((B0+B1)+(B2+B3)), numpy's exact tree
    }
    if (lane == 0) {
        float mean = r * (1.0f / 512.0f);          // /512 exact
        float v    = mean + 0.25f * mean;          // == el + BETA*cl bitwise
        out[(size_t)N_ROWS * DIM + row]          = v;            // vq_loss
        out[(size_t)N_ROWS * DIM + N_ROWS + row] = (float)idx;   // inds
        if (gold[row] == idx) atomicAdd(counter, 1);
    }
}

__global__ void tail_kernel(const int* __restrict__ counter,
                            float* __restrict__ out) {
    if (threadIdx.x == 0 && blockIdx.x == 0) {
        const size_t off = (size_t)N_ROWS * DIM + 2 * (size_t)N_ROWS;
        out[off]     = (float)(*counter);   // correct
        out[off + 1] = (float)N_ROWS;       // total
    }
}

// ---------------------------------------------------------------------------
extern "C" void kernel_launch(void* const* d_in, const int* in_sizes, int n_in,
                              void* d_out, int out_size, void* d_ws, size_t ws_size,
                              hipStream_t stream) {
    (void)in_sizes; (void)n_in; (void)out_size; (void)ws_size;
    const int*   gold = (const int*)d_in[0];
    const float* lat  = (const float*)d_in[1];
    // d_in[2] = epc, unused by the reference outputs
    const float* emb  = (const float*)d_in[3];
    float* out = (float*)d_out;

    float* row_sq  = (float*)d_ws;
    float* emb_sq  = row_sq + N_ROWS;
    int*   enc     = (int*)(emb_sq + KCB);
    int*   counter = enc + N_ROWS;

    hipMemsetAsync(counter, 0, sizeof(int), stream);
    sq_kernel<<<(N_ROWS + KCB + 255) / 256, 256, 0, stream>>>(lat, emb, row_sq, emb_sq);
    dist_kernel<<<N_ROWS / BM, 256, 0, stream>>>(lat, emb, row_sq, emb_sq, enc);
    out_kernel<<<N_ROWS / 4, 256, 0, stream>>>(lat, emb, gold, enc, out, counter);
    tail_kernel<<<1, 64, 0, stream>>>(counter, out);
}

// Round 2
// 1480.414 us; speedup vs baseline: 3.2076x; 3.2076x over previous
//
#include <hip/hip_runtime.h>
#include <math.h>

#define N_ROWS 32768
#define KCB    8192
#define DIM    512
#define BETA   0.25f
#define MARGIN 5e-4f

typedef __attribute__((ext_vector_type(8))) short  bf16x8;
typedef __attribute__((ext_vector_type(4))) float  f32x4;

// ---------------------------------------------------------------------------
// Kernel 1: ||x||^2 / ||e||^2 with numpy's exact pairwise-summation tree.
// ---------------------------------------------------------------------------
__global__ void sq_kernel(const float* __restrict__ lat,
                          const float* __restrict__ emb,
                          float* __restrict__ row_sq,
                          float* __restrict__ emb_sq) {
#pragma clang fp contract(off)
    int row = blockIdx.x * blockDim.x + threadIdx.x;
    const int total = N_ROWS + KCB;
    if (row >= total) return;
    const float* p = (row < N_ROWS) ? (lat + (size_t)row * DIM)
                                    : (emb + (size_t)(row - N_ROWS) * DIM);
    float B[4];
    for (int b = 0; b < 4; ++b) {
        const float* q = p + b * 128;
        float r[8];
        for (int j = 0; j < 8; ++j) { float a = q[j]; r[j] = a * a; }
        for (int i = 1; i < 16; ++i)
            for (int j = 0; j < 8; ++j) {
                float a = q[8 * i + j];
                float s = a * a;
                r[j] = r[j] + s;
            }
        B[b] = ((r[0] + r[1]) + (r[2] + r[3])) + ((r[4] + r[5]) + (r[6] + r[7]));
    }
    float s = (B[0] + B[1]) + (B[2] + B[3]);
    if (row < N_ROWS) row_sq[row] = s;
    else              emb_sq[row - N_ROWS] = s;
}

// ---------------------------------------------------------------------------
// Kernel 2: fp32 -> bf16 (RNE) copies of lat and emb into ws.
// ---------------------------------------------------------------------------
__device__ __forceinline__ unsigned short f2bf(float f) {
    unsigned u = __float_as_uint(f);
    return (unsigned short)((u + 0x7FFFu + ((u >> 16) & 1u)) >> 16);
}

__global__ void cvt_kernel(const float* __restrict__ lat,
                           const float* __restrict__ emb,
                           unsigned short* __restrict__ latb,
                           unsigned short* __restrict__ embb) {
    const size_t NL8 = (size_t)N_ROWS * DIM / 8;
    const size_t NE8 = (size_t)KCB * DIM / 8;
    size_t g = (size_t)blockIdx.x * 256 + threadIdx.x;
    const float* src; unsigned short* dst; size_t i;
    if (g < NL8)            { src = lat; dst = latb; i = g; }
    else if (g < NL8 + NE8) { src = emb; dst = embb; i = g - NL8; }
    else return;
    float4 v0 = ((const float4*)src)[2 * i];
    float4 v1 = ((const float4*)src)[2 * i + 1];
    ushort4 o0 = { f2bf(v0.x), f2bf(v0.y), f2bf(v0.z), f2bf(v0.w) };
    ushort4 o1 = { f2bf(v1.x), f2bf(v1.y), f2bf(v1.z), f2bf(v1.w) };
    ((ushort4*)dst)[2 * i]     = o0;
    ((ushort4*)dst)[2 * i + 1] = o1;
}

// ---------------------------------------------------------------------------
// Kernel 3: bf16 MFMA GEMM, 128x128 tile, epilogue -> per-(row, 32-code
// group) min of approx score (sx+se-2*dot). LDS layout [kgroup][row][8bf16]
// so frag reads are conflict-free ds_read_b128 and global_load_lds staging
// is lane-contiguous.
// ---------------------------------------------------------------------------
__device__ __forceinline__ void load16_to_lds(const void* g, void* l) {
    __builtin_amdgcn_global_load_lds(
        (const __attribute__((address_space(1))) unsigned int*)g,
        (__attribute__((address_space(3))) unsigned int*)l, 16, 0, 0);
}

__global__ __launch_bounds__(256) void gemm_kernel(
        const unsigned short* __restrict__ latb,
        const unsigned short* __restrict__ embb,
        const float* __restrict__ row_sq,
        const float* __restrict__ emb_sq,
        float* __restrict__ tilemin) {
    __shared__ unsigned short As[8 * 128 * 8];   // [kg][row][8] bf16, 16 KB
    __shared__ unsigned short Bs[8 * 128 * 8];

    const int tid  = threadIdx.x;
    const int w    = tid >> 6;
    const int lane = tid & 63;
    const int q    = lane >> 4;
    const int m16  = lane & 15;
    const int row0 = blockIdx.x * 128;
    const int n0   = blockIdx.y * 128;
    const int wr0  = (w >> 1) * 64;
    const int wc0  = (w & 1) * 64;

    f32x4 acc[4][4];
#pragma unroll
    for (int r = 0; r < 4; ++r)
#pragma unroll
        for (int c = 0; c < 4; ++c) acc[r][c] = (f32x4){0.f, 0.f, 0.f, 0.f};

    for (int k0 = 0; k0 < DIM; k0 += 64) {
        // stage: 32 chunks of (64 rows x 8 bf16); wave w issues chunks w*8..+7
#pragma unroll
        for (int i = 0; i < 8; ++i) {
            int cid = w * 8 + i;
            if (cid < 16) {
                int kg = cid >> 1, h = cid & 1;
                const unsigned short* g = latb +
                    (size_t)(row0 + h * 64 + lane) * DIM + k0 + kg * 8;
                load16_to_lds(g, &As[(kg * 128 + h * 64) * 8]);
            } else {
                int c2 = cid - 16, kg = c2 >> 1, h = c2 & 1;
                const unsigned short* g = embb +
                    (size_t)(n0 + h * 64 + lane) * DIM + k0 + kg * 8;
                load16_to_lds(g, &Bs[(kg * 128 + h * 64) * 8]);
            }
        }
        __syncthreads();
#pragma unroll
        for (int kk = 0; kk < 2; ++kk) {
            bf16x8 a[4], b[4];
#pragma unroll
            for (int r = 0; r < 4; ++r)
                a[r] = *(const bf16x8*)&As[((4 * kk + q) * 128 + wr0 + 16 * r + m16) * 8];
#pragma unroll
            for (int c = 0; c < 4; ++c)
                b[c] = *(const bf16x8*)&Bs[((4 * kk + q) * 128 + wc0 + 16 * c + m16) * 8];
#pragma unroll
            for (int r = 0; r < 4; ++r)
#pragma unroll
                for (int c = 0; c < 4; ++c)
                    acc[r][c] = __builtin_amdgcn_mfma_f32_16x16x32_bf16(
                        a[r], b[c], acc[r][c], 0, 0, 0);
        }
        __syncthreads();
    }

    // epilogue: score = (sx+se) - 2*dot; per-(row, 32-col group) min
    float sxv[4][4], sev[4];
#pragma unroll
    for (int r = 0; r < 4; ++r)
#pragma unroll
        for (int reg = 0; reg < 4; ++reg)
            sxv[r][reg] = row_sq[row0 + wr0 + 16 * r + 4 * q + reg];
#pragma unroll
    for (int c = 0; c < 4; ++c)
        sev[c] = emb_sq[n0 + wc0 + 16 * c + m16];

#pragma unroll
    for (int r = 0; r < 4; ++r)
#pragma unroll
        for (int reg = 0; reg < 4; ++reg) {
#pragma unroll
            for (int g = 0; g < 2; ++g) {
                float s0 = (sxv[r][reg] + sev[2 * g])     - 2.0f * acc[r][2 * g][reg];
                float s1 = (sxv[r][reg] + sev[2 * g + 1]) - 2.0f * acc[r][2 * g + 1][reg];
                float mn = fminf(s0, s1);
#pragma unroll
                for (int off = 1; off < 16; off <<= 1)
                    mn = fminf(mn, __shfl_xor(mn, off));
                if (m16 == 0) {
                    int grow = row0 + wr0 + 16 * r + 4 * q + reg;
                    int gcol = 4 * blockIdx.y + 2 * (w & 1) + g;
                    tilemin[(size_t)grow * 256 + gcol] = mn;
                }
            }
        }
}

// ---------------------------------------------------------------------------
// Kernel 4: per row: m = min(tilemin), exact fp32 rescoring of flagged
// 32-code groups using the IDENTICAL rounding chain as the R1 kernel
// (sequential fmaf over ascending d; dist = (sx+se) - 2*acc). Lowest-index
// tie-break. One wave per row.
// ---------------------------------------------------------------------------
__global__ __launch_bounds__(256) void argmin_kernel(
        const float* __restrict__ lat, const float* __restrict__ emb,
        const float* __restrict__ row_sq, const float* __restrict__ emb_sq,
        const float* __restrict__ tilemin, int* __restrict__ enc) {
    __shared__ float xs[4][DIM];
    const int w    = threadIdx.x >> 6;
    const int lane = threadIdx.x & 63;
    const int row  = blockIdx.x * 4 + w;

    // stage x row into this wave's LDS slab
    {
        const float4* xp = (const float4*)(lat + (size_t)row * DIM);
        ((float4*)xs[w])[lane]      = xp[lane];
        ((float4*)xs[w])[lane + 64] = xp[lane + 64];
    }
    const float sx = row_sq[row];

    // group mins: lane holds groups 4*lane .. 4*lane+3
    float4 tv = ((const float4*)(tilemin + (size_t)row * 256))[lane];
    float tm[4] = { tv.x, tv.y, tv.z, tv.w };
    float m = fminf(fminf(tm[0], tm[1]), fminf(tm[2], tm[3]));
#pragma unroll
    for (int off = 1; off < 64; off <<= 1)
        m = fminf(m, __shfl_xor(m, off));
    const float thresh = m + MARGIN;

    float bd = INFINITY;
    int   bi = 0x7fffffff;
    const float* xw = xs[w];

    for (int g4 = 0; g4 < 64; ++g4) {
#pragma unroll
        for (int j = 0; j < 4; ++j) {
            float tg = __shfl(tm[j], g4);          // uniform across wave
            if (tg <= thresh) {
                int G = 4 * g4 + j;
                float dvl = INFINITY;
                int   cl  = 0x7fffffff;
                if (lane < 32) {
                    int code = G * 32 + lane;
                    const float* ep = emb + (size_t)code * DIM;
                    float acc = 0.0f;
                    for (int d = 0; d < DIM; d += 8) {
                        float ev[8], xv[8];
#pragma unroll
                        for (int t = 0; t < 8; ++t) { ev[t] = ep[d + t]; xv[t] = xw[d + t]; }
#pragma unroll
                        for (int t = 0; t < 8; ++t) acc = fmaf(xv[t], ev[t], acc);
                    }
                    float a = sx + emb_sq[code];
                    dvl = a - 2.0f * acc;
                    cl  = code;
                }
                if (dvl < bd || (dvl == bd && cl < bi)) { bd = dvl; bi = cl; }
            }
        }
    }
#pragma unroll
    for (int off = 1; off < 64; off <<= 1) {
        float od = __shfl_xor(bd, off);
        int   oi = __shfl_xor(bi, off);
        if (od < bd || (od == bd && oi < bi)) { bd = od; bi = oi; }
    }
    if (lane == 0) enc[row] = bi;
}

// ---------------------------------------------------------------------------
// R1 fallback dist kernel (used only if ws_size is too small for bf16 path)
// ---------------------------------------------------------------------------
#define BM 64
#define BK 128
#define BD 32
__global__ __launch_bounds__(256) void dist_kernel(
        const float* __restrict__ lat, const float* __restrict__ emb,
        const float* __restrict__ row_sq, const float* __restrict__ emb_sq,
        int* __restrict__ enc) {
    __shared__ float xs[BD][BM];
    __shared__ float es[BD][BK];
    const int tid  = threadIdx.x;
    const int trow = tid >> 4;
    const int tcol = tid & 15;
    const int row0 = blockIdx.x * BM;
    float bd[4]; int bi[4];
    for (int i = 0; i < 4; ++i) { bd[i] = INFINITY; bi[i] = 0; }
    float sx[4];
    for (int i = 0; i < 4; ++i) sx[i] = row_sq[row0 + 4 * trow + i];
    for (int kt = 0; kt < KCB; kt += BK) {
        float acc[4][8] = {};
        for (int d0 = 0; d0 < DIM; d0 += BD) {
            for (int f = tid; f < BM * BD / 4; f += 256) {
                int r = f >> 3, c4 = f & 7;
                float4 v = *(const float4*)(lat + (size_t)(row0 + r) * DIM + d0 + 4 * c4);
                xs[4 * c4 + 0][r] = v.x; xs[4 * c4 + 1][r] = v.y;
                xs[4 * c4 + 2][r] = v.z; xs[4 * c4 + 3][r] = v.w;
            }
            for (int f = tid; f < BK * BD / 4; f += 256) {
                int r = f >> 3, c4 = f & 7;
                float4 v = *(const float4*)(emb + (size_t)(kt + r) * DIM + d0 + 4 * c4);
                es[4 * c4 + 0][r] = v.x; es[4 * c4 + 1][r] = v.y;
                es[4 * c4 + 2][r] = v.z; es[4 * c4 + 3][r] = v.w;
            }
            __syncthreads();
            for (int dd = 0; dd < BD; ++dd) {
                float4 xv  = *(const float4*)&xs[dd][4 * trow];
                float4 ev0 = *(const float4*)&es[dd][8 * tcol];
                float4 ev1 = *(const float4*)&es[dd][8 * tcol + 4];
                float xr[4] = { xv.x, xv.y, xv.z, xv.w };
                float ec[8] = { ev0.x, ev0.y, ev0.z, ev0.w, ev1.x, ev1.y, ev1.z, ev1.w };
                for (int r = 0; r < 4; ++r)
                    for (int c = 0; c < 8; ++c)
                        acc[r][c] = fmaf(xr[r], ec[c], acc[r][c]);
            }
            __syncthreads();
        }
        for (int c = 0; c < 8; ++c) {
            int   code = kt + 8 * tcol + c;
            float se   = emb_sq[code];
            for (int r = 0; r < 4; ++r) {
                float a  = sx[r] + se;
                float dv = a - 2.0f * acc[r][c];
                if (dv < bd[r]) { bd[r] = dv; bi[r] = code; }
            }
        }
    }
    for (int off = 1; off < 16; off <<= 1) {
        for (int r = 0; r < 4; ++r) {
            float od = __shfl_xor(bd[r], off);
            int   oi = __shfl_xor(bi[r], off);
            if (od < bd[r] || (od == bd[r] && oi < bi[r])) { bd[r] = od; bi[r] = oi; }
        }
    }
    if (tcol == 0)
        for (int r = 0; r < 4; ++r)
            enc[row0 + 4 * trow + r] = bi[r];
}

// ---------------------------------------------------------------------------
// Kernel 5: outputs (unchanged from R1 — passed).
// ---------------------------------------------------------------------------
__global__ void out_kernel(const float* __restrict__ lat,
                           const float* __restrict__ emb,
                           const int* __restrict__ gold,
                           const int* __restrict__ enc,
                           float* __restrict__ out,
                           int* __restrict__ counter) {
#pragma clang fp contract(off)
    const int gid  = blockIdx.x * blockDim.x + threadIdx.x;
    const int row  = gid >> 6;
    const int lane = threadIdx.x & 63;
    if (row >= N_ROWS) return;
    const int idx = enc[row];
    const float4* e4 = (const float4*)(emb + (size_t)idx * DIM);
    float4*       q4 = (float4*)(out + (size_t)row * DIM);
    q4[lane]      = e4[lane];
    q4[lane + 64] = e4[lane + 64];
    float r = 0.0f;
    if (lane < 32) {
        const int b = lane >> 3, j = lane & 7;
        const float* ep = emb + (size_t)idx * DIM + b * 128 + j;
        const float* xp = lat + (size_t)row * DIM + b * 128 + j;
        for (int i = 0; i < 16; ++i) {
            float dq = ep[8 * i] - xp[8 * i];
            float s  = dq * dq;
            r = (i == 0) ? s : (r + s);
        }
    }
    for (int m = 1; m <= 16; m <<= 1) {
        float o = __shfl_xor(r, m);
        r = r + o;
    }
    if (lane == 0) {
        float mean = r * (1.0f / 512.0f);
        float v    = mean + 0.25f * mean;
        out[(size_t)N_ROWS * DIM + row]          = v;
        out[(size_t)N_ROWS * DIM + N_ROWS + row] = (float)idx;
        if (gold[row] == idx) atomicAdd(counter, 1);
    }
}

__global__ void tail_kernel(const int* __restrict__ counter,
                            float* __restrict__ out) {
    if (threadIdx.x == 0 && blockIdx.x == 0) {
        const size_t off = (size_t)N_ROWS * DIM + 2 * (size_t)N_ROWS;
        out[off]     = (float)(*counter);
        out[off + 1] = (float)N_ROWS;
    }
}

// ---------------------------------------------------------------------------
extern "C" void kernel_launch(void* const* d_in, const int* in_sizes, int n_in,
                              void* d_out, int out_size, void* d_ws, size_t ws_size,
                              hipStream_t stream) {
    (void)in_sizes; (void)n_in; (void)out_size;
    const int*   gold = (const int*)d_in[0];
    const float* lat  = (const float*)d_in[1];
    const float* emb  = (const float*)d_in[3];
    float* out = (float*)d_out;

    const size_t SZ_LATB = (size_t)N_ROWS * DIM * 2;   // 33554432
    const size_t SZ_EMBB = (size_t)KCB * DIM * 2;      //  8388608
    const size_t SZ_TM   = (size_t)N_ROWS * 256 * 4;   // 33554432
    const size_t NEEDED  = SZ_LATB + SZ_EMBB + SZ_TM +
                           (size_t)N_ROWS * 4 + (size_t)KCB * 4 +
                           (size_t)N_ROWS * 4 + 256;

    if (ws_size >= NEEDED) {
        unsigned char* w8 = (unsigned char*)d_ws;
        unsigned short* latb    = (unsigned short*)w8;
        unsigned short* embb    = (unsigned short*)(w8 + SZ_LATB);
        float*          tilemin = (float*)(w8 + SZ_LATB + SZ_EMBB);
        float*          row_sq  = (float*)(w8 + SZ_LATB + SZ_EMBB + SZ_TM);
        float*          emb_sq  = row_sq + N_ROWS;
        int*            enc     = (int*)(emb_sq + KCB);
        int*            counter = enc + N_ROWS;

        hipMemsetAsync(counter, 0, sizeof(int), stream);
        sq_kernel<<<(N_ROWS + KCB + 255) / 256, 256, 0, stream>>>(lat, emb, row_sq, emb_sq);
        cvt_kernel<<<(N_ROWS + KCB) * DIM / 8 / 256, 256, 0, stream>>>(lat, emb, latb, embb);
        gemm_kernel<<<dim3(N_ROWS / 128, KCB / 128), 256, 0, stream>>>(
            latb, embb, row_sq, emb_sq, tilemin);
        argmin_kernel<<<N_ROWS / 4, 256, 0, stream>>>(lat, emb, row_sq, emb_sq, tilemin, enc);
        out_kernel<<<N_ROWS / 4, 256, 0, stream>>>(lat, emb, gold, enc, out, counter);
        tail_kernel<<<1, 64, 0, stream>>>(counter, out);
    } else {
        float* row_sq  = (float*)d_ws;
        float* emb_sq  = row_sq + N_ROWS;
        int*   enc     = (int*)(emb_sq + KCB);
        int*   counter = enc + N_ROWS;
        hipMemsetAsync(counter, 0, sizeof(int), stream);
        sq_kernel<<<(N_ROWS + KCB + 255) / 256, 256, 0, stream>>>(lat, emb, row_sq, emb_sq);
        dist_kernel<<<N_ROWS / BM, 256, 0, stream>>>(lat, emb, row_sq, emb_sq, enc);
        out_kernel<<<N_ROWS / 4, 256, 0, stream>>>(lat, emb, gold, enc, out, counter);
        tail_kernel<<<1, 64, 0, stream>>>(counter, out);
    }
}

// Round 3
// 1382.248 us; speedup vs baseline: 3.4354x; 1.0710x over previous
//
#include <hip/hip_runtime.h>
#include <math.h>

#define N_ROWS 32768
#define KCB    8192
#define DIM    512
#define BETA   0.25f
#define MARGIN 3e-4f
#define NITER  4          // code-tiles per gemm block (BN_eff = 512)

typedef __attribute__((ext_vector_type(8))) short  bf16x8;
typedef __attribute__((ext_vector_type(4))) float  f32x4;

// ---------------------------------------------------------------------------
// Kernel 1: ||x||^2 / ||e||^2, numpy-exact pairwise tree, wave-parallel.
// Lane layout per 32-lane half-wave (1 row each): b=L>>3 (128-block),
// j=L&7 (accumulator). Butterfly shfl_xor reproduces R1's exact combine
// tree (fp add is commutative, so partner-order is bitwise identical).
// ---------------------------------------------------------------------------
__global__ __launch_bounds__(256) void sq_kernel(
        const float* __restrict__ lat, const float* __restrict__ emb,
        float* __restrict__ row_sq, float* __restrict__ emb_sq) {
#pragma clang fp contract(off)
    const int w    = threadIdx.x >> 6;
    const int lane = threadIdx.x & 63;
    const int half = lane >> 5;
    const int L    = lane & 31;
    const int b    = L >> 3, j = L & 7;
    const int row  = blockIdx.x * 8 + w * 2 + half;
    const int total = N_ROWS + KCB;
    if (row >= total) return;
    const float* p = (row < N_ROWS) ? (lat + (size_t)row * DIM)
                                    : (emb + (size_t)(row - N_ROWS) * DIM);
    const float* q = p + 128 * b + j;
    float a0 = q[0];
    float r  = a0 * a0;
    for (int i = 1; i < 16; ++i) {
        float a = q[8 * i];
        float s = a * a;
        r = r + s;
    }
    // combine r[0..7] -> B[b] with tree ((r0+r1)+(r2+r3))+((r4+r5)+(r6+r7))
    r = r + __shfl_xor(r, 1);
    r = r + __shfl_xor(r, 2);
    r = r + __shfl_xor(r, 4);
    // s = (B0+B1)+(B2+B3)
    r = r + __shfl_xor(r, 8);
    r = r + __shfl_xor(r, 16);
    if (L == 0) {
        if (row < N_ROWS) row_sq[row] = r;
        else              emb_sq[row - N_ROWS] = r;
    }
}

// ---------------------------------------------------------------------------
// Kernel 2: fp32 -> bf16 (RNE) copies.
// ---------------------------------------------------------------------------
__device__ __forceinline__ unsigned short f2bf(float f) {
    unsigned u = __float_as_uint(f);
    return (unsigned short)((u + 0x7FFFu + ((u >> 16) & 1u)) >> 16);
}

__global__ void cvt_kernel(const float* __restrict__ lat,
                           const float* __restrict__ emb,
                           unsigned short* __restrict__ latb,
                           unsigned short* __restrict__ embb) {
    const size_t NL8 = (size_t)N_ROWS * DIM / 8;
    const size_t NE8 = (size_t)KCB * DIM / 8;
    size_t g = (size_t)blockIdx.x * 256 + threadIdx.x;
    const float* src; unsigned short* dst; size_t i;
    if (g < NL8)            { src = lat; dst = latb; i = g; }
    else if (g < NL8 + NE8) { src = emb; dst = embb; i = g - NL8; }
    else return;
    float4 v0 = ((const float4*)src)[2 * i];
    float4 v1 = ((const float4*)src)[2 * i + 1];
    ushort4 o0 = { f2bf(v0.x), f2bf(v0.y), f2bf(v0.z), f2bf(v0.w) };
    ushort4 o1 = { f2bf(v1.x), f2bf(v1.y), f2bf(v1.z), f2bf(v1.w) };
    ((ushort4*)dst)[2 * i]     = o0;
    ((ushort4*)dst)[2 * i + 1] = o1;
}

// ---------------------------------------------------------------------------
// Kernel 3: bf16 MFMA GEMM. 256x128 tile x NITER code-tiles per block,
// 512 threads (8 waves, 64x64 each). A-tile re-staged per n-iter from
// L2-hot lines; B streamed. Epilogue: per-(row, GS-code group) min of
// approx score. NG = groups per row (512 -> GS=16, 256 -> GS=32).
// ---------------------------------------------------------------------------
__device__ __forceinline__ void load16_to_lds(const void* g, void* l) {
    __builtin_amdgcn_global_load_lds(
        (const __attribute__((address_space(1))) unsigned int*)g,
        (__attribute__((address_space(3))) unsigned int*)l, 16, 0, 0);
}

template<int NG>
__global__ __launch_bounds__(512) void gemm_kernel(
        const unsigned short* __restrict__ latb,
        const unsigned short* __restrict__ embb,
        const float* __restrict__ row_sq,
        const float* __restrict__ emb_sq,
        float* __restrict__ tilemin) {
    __shared__ unsigned short As[8 * 256 * 8];   // 32 KB [kg][row][8]
    __shared__ unsigned short Bs[8 * 128 * 8];   // 16 KB

    const int tid  = threadIdx.x;
    const int w    = tid >> 6;
    const int lane = tid & 63;
    const int q    = lane >> 4;
    const int m16  = lane & 15;
    const int row0 = blockIdx.x * 256;
    const int nbase = blockIdx.y * (NITER * 128);
    const int wr0  = (w >> 1) * 64;
    const int wc0  = (w & 1) * 64;

    float sxv[4][4];
#pragma unroll
    for (int r = 0; r < 4; ++r)
#pragma unroll
        for (int reg = 0; reg < 4; ++reg)
            sxv[r][reg] = row_sq[row0 + wr0 + 16 * r + 4 * q + reg];

    for (int ni = 0; ni < NITER; ++ni) {
        const int n0 = nbase + ni * 128;
        float sev[4];
#pragma unroll
        for (int c = 0; c < 4; ++c)
            sev[c] = emb_sq[n0 + wc0 + 16 * c + m16];

        f32x4 acc[4][4];
#pragma unroll
        for (int r = 0; r < 4; ++r)
#pragma unroll
            for (int c = 0; c < 4; ++c) acc[r][c] = (f32x4){0.f, 0.f, 0.f, 0.f};

        for (int k0 = 0; k0 < DIM; k0 += 64) {
#pragma unroll
            for (int i = 0; i < 6; ++i) {
                int cid = w * 6 + i;
                if (cid < 32) {
                    int kg = cid >> 2, h = cid & 3;
                    const unsigned short* g = latb +
                        (size_t)(row0 + h * 64 + lane) * DIM + k0 + kg * 8;
                    load16_to_lds(g, &As[(kg * 256 + h * 64) * 8]);
                } else {
                    int c2 = cid - 32, kg = c2 >> 1, h = c2 & 1;
                    const unsigned short* g = embb +
                        (size_t)(n0 + h * 64 + lane) * DIM + k0 + kg * 8;
                    load16_to_lds(g, &Bs[(kg * 128 + h * 64) * 8]);
                }
            }
            __syncthreads();
#pragma unroll
            for (int kk = 0; kk < 2; ++kk) {
                bf16x8 a[4], b[4];
#pragma unroll
                for (int r = 0; r < 4; ++r)
                    a[r] = *(const bf16x8*)&As[((4 * kk + q) * 256 + wr0 + 16 * r + m16) * 8];
#pragma unroll
                for (int c = 0; c < 4; ++c)
                    b[c] = *(const bf16x8*)&Bs[((4 * kk + q) * 128 + wc0 + 16 * c + m16) * 8];
#pragma unroll
                for (int r = 0; r < 4; ++r)
#pragma unroll
                    for (int c = 0; c < 4; ++c)
                        acc[r][c] = __builtin_amdgcn_mfma_f32_16x16x32_bf16(
                            a[r], b[c], acc[r][c], 0, 0, 0);
            }
            __syncthreads();
        }

        // epilogue: per-(row, group) min
#pragma unroll
        for (int r = 0; r < 4; ++r)
#pragma unroll
            for (int reg = 0; reg < 4; ++reg) {
                int grow = row0 + wr0 + 16 * r + 4 * q + reg;
                if (NG == 512) {
#pragma unroll
                    for (int c = 0; c < 4; ++c) {
                        float s = (sxv[r][reg] + sev[c]) - 2.0f * acc[r][c][reg];
#pragma unroll
                        for (int off = 1; off < 16; off <<= 1)
                            s = fminf(s, __shfl_xor(s, off));
                        if (m16 == 0)
                            tilemin[(size_t)grow * 512 + (n0 >> 4) + (w & 1) * 4 + c] = s;
                    }
                } else {
#pragma unroll
                    for (int g = 0; g < 2; ++g) {
                        float s0 = (sxv[r][reg] + sev[2 * g])     - 2.0f * acc[r][2 * g][reg];
                        float s1 = (sxv[r][reg] + sev[2 * g + 1]) - 2.0f * acc[r][2 * g + 1][reg];
                        float mn = fminf(s0, s1);
#pragma unroll
                        for (int off = 1; off < 16; off <<= 1)
                            mn = fminf(mn, __shfl_xor(mn, off));
                        if (m16 == 0)
                            tilemin[(size_t)grow * 256 + (n0 >> 5) + (w & 1) * 2 + g] = mn;
                    }
                }
            }
        __syncthreads();
    }
}

// ---------------------------------------------------------------------------
// Kernel 4 (fused): per row: global min of group-mins; exact fp32 rescore of
// flagged groups with R1's bit-identical chain; then quantized row write,
// vq_loss (numpy-exact tree, lat read from LDS), inds, correct-count.
// One wave per row, 4 rows per block.
// ---------------------------------------------------------------------------
template<int NG>
__global__ __launch_bounds__(256) void argmin_out_kernel(
        const float* __restrict__ lat, const float* __restrict__ emb,
        const float* __restrict__ row_sq, const float* __restrict__ emb_sq,
        const float* __restrict__ tilemin,
        const int* __restrict__ gold,
        float* __restrict__ out, int* __restrict__ counter) {
    constexpr int GS = KCB / NG;     // codes per group (16 or 32)
    constexpr int PL = NG / 64;      // group-mins per lane (8 or 4)
    __shared__ float xs[4][DIM];
    const int w    = threadIdx.x >> 6;
    const int lane = threadIdx.x & 63;
    const int row  = blockIdx.x * 4 + w;

    {
        const float4* xp = (const float4*)(lat + (size_t)row * DIM);
        ((float4*)xs[w])[lane]      = xp[lane];
        ((float4*)xs[w])[lane + 64] = xp[lane + 64];
    }
    const float sx = row_sq[row];
    const float* xw = xs[w];

    float tm[PL];
    {
        const float4* tb = (const float4*)(tilemin + (size_t)row * NG + lane * PL);
#pragma unroll
        for (int j4 = 0; j4 < PL / 4; ++j4) {
            float4 v = tb[j4];
            tm[4 * j4 + 0] = v.x; tm[4 * j4 + 1] = v.y;
            tm[4 * j4 + 2] = v.z; tm[4 * j4 + 3] = v.w;
        }
    }
    float m = tm[0];
#pragma unroll
    for (int j = 1; j < PL; ++j) m = fminf(m, tm[j]);
#pragma unroll
    for (int off = 1; off < 64; off <<= 1)
        m = fminf(m, __shfl_xor(m, off));
    const float thresh = m + MARGIN;

    float bd = INFINITY;
    int   bi = 0x7fffffff;
#pragma unroll
    for (int j = 0; j < PL; ++j) {
        unsigned long long mask = __ballot(tm[j] <= thresh);
        while (mask) {
            int l = __ffsll(mask) - 1;
            mask &= mask - 1;
            int G = l * PL + j;
            float dvl = INFINITY;
            int   cl  = 0x7fffffff;
            if (lane < GS) {
                int code = G * GS + lane;
                const float* ep = emb + (size_t)code * DIM;
                float acc = 0.0f;
                for (int d = 0; d < DIM; d += 8) {
                    float ev[8], xv[8];
#pragma unroll
                    for (int t = 0; t < 8; ++t) { ev[t] = ep[d + t]; xv[t] = xw[d + t]; }
#pragma unroll
                    for (int t = 0; t < 8; ++t) acc = fmaf(xv[t], ev[t], acc);
                }
                float a = sx + emb_sq[code];
                dvl = a - 2.0f * acc;
                cl  = code;
            }
            if (dvl < bd || (dvl == bd && cl < bi)) { bd = dvl; bi = cl; }
        }
    }
#pragma unroll
    for (int off = 1; off < 64; off <<= 1) {
        float od = __shfl_xor(bd, off);
        int   oi = __shfl_xor(bi, off);
        if (od < bd || (od == bd && oi < bi)) { bd = od; bi = oi; }
    }
    const int idx = bi;

    // quantized = emb[idx]
    const float4* e4 = (const float4*)(emb + (size_t)idx * DIM);
    float4*       q4 = (float4*)(out + (size_t)row * DIM);
    q4[lane]      = e4[lane];
    q4[lane + 64] = e4[lane + 64];

    // vq_loss with R1's exact tree (lat values from LDS, bitwise identical)
    float r = 0.0f;
    if (lane < 32) {
        const int b = lane >> 3, j = lane & 7;
        const float* ep = emb + (size_t)idx * DIM + b * 128 + j;
        const float* xp = xw + b * 128 + j;
        for (int i = 0; i < 16; ++i) {
            float dq = ep[8 * i] - xp[8 * i];
            float s  = dq * dq;
            r = (i == 0) ? s : (r + s);
        }
    }
    for (int mm = 1; mm <= 16; mm <<= 1) {
        float o = __shfl_xor(r, mm);
        r = r + o;
    }
    if (lane == 0) {
        float mean = r * (1.0f / 512.0f);
        float v    = mean + 0.25f * mean;
        out[(size_t)N_ROWS * DIM + row]          = v;
        out[(size_t)N_ROWS * DIM + N_ROWS + row] = (float)idx;
        if (gold[row] == idx) atomicAdd(counter, 1);
    }
}

__global__ void tail_kernel(const int* __restrict__ counter,
                            float* __restrict__ out) {
    if (threadIdx.x == 0 && blockIdx.x == 0) {
        const size_t off = (size_t)N_ROWS * DIM + 2 * (size_t)N_ROWS;
        out[off]     = (float)(*counter);
        out[off + 1] = (float)N_ROWS;
    }
}

// ---------------------------------------------------------------------------
// R1 fallback path (tiny-ws only): fp32 dist + separate out kernel.
// ---------------------------------------------------------------------------
#define BM 64
#define BK 128
#define BD 32
__global__ __launch_bounds__(256) void dist_kernel(
        const float* __restrict__ lat, const float* __restrict__ emb,
        const float* __restrict__ row_sq, const float* __restrict__ emb_sq,
        int* __restrict__ enc) {
    __shared__ float xsh[BD][BM];
    __shared__ float esh[BD][BK];
    const int tid  = threadIdx.x;
    const int trow = tid >> 4;
    const int tcol = tid & 15;
    const int row0 = blockIdx.x * BM;
    float bd[4]; int bi[4];
    for (int i = 0; i < 4; ++i) { bd[i] = INFINITY; bi[i] = 0; }
    float sx[4];
    for (int i = 0; i < 4; ++i) sx[i] = row_sq[row0 + 4 * trow + i];
    for (int kt = 0; kt < KCB; kt += BK) {
        float acc[4][8] = {};
        for (int d0 = 0; d0 < DIM; d0 += BD) {
            for (int f = tid; f < BM * BD / 4; f += 256) {
                int r = f >> 3, c4 = f & 7;
                float4 v = *(const float4*)(lat + (size_t)(row0 + r) * DIM + d0 + 4 * c4);
                xsh[4 * c4 + 0][r] = v.x; xsh[4 * c4 + 1][r] = v.y;
                xsh[4 * c4 + 2][r] = v.z; xsh[4 * c4 + 3][r] = v.w;
            }
            for (int f = tid; f < BK * BD / 4; f += 256) {
                int r = f >> 3, c4 = f & 7;
                float4 v = *(const float4*)(emb + (size_t)(kt + r) * DIM + d0 + 4 * c4);
                esh[4 * c4 + 0][r] = v.x; esh[4 * c4 + 1][r] = v.y;
                esh[4 * c4 + 2][r] = v.z; esh[4 * c4 + 3][r] = v.w;
            }
            __syncthreads();
            for (int dd = 0; dd < BD; ++dd) {
                float4 xv  = *(const float4*)&xsh[dd][4 * trow];
                float4 ev0 = *(const float4*)&esh[dd][8 * tcol];
                float4 ev1 = *(const float4*)&esh[dd][8 * tcol + 4];
                float xr[4] = { xv.x, xv.y, xv.z, xv.w };
                float ec[8] = { ev0.x, ev0.y, ev0.z, ev0.w, ev1.x, ev1.y, ev1.z, ev1.w };
                for (int r = 0; r < 4; ++r)
                    for (int c = 0; c < 8; ++c)
                        acc[r][c] = fmaf(xr[r], ec[c], acc[r][c]);
            }
            __syncthreads();
        }
        for (int c = 0; c < 8; ++c) {
            int   code = kt + 8 * tcol + c;
            float se   = emb_sq[code];
            for (int r = 0; r < 4; ++r) {
                float a  = sx[r] + se;
                float dv = a - 2.0f * acc[r][c];
                if (dv < bd[r]) { bd[r] = dv; bi[r] = code; }
            }
        }
    }
    for (int off = 1; off < 16; off <<= 1) {
        for (int r = 0; r < 4; ++r) {
            float od = __shfl_xor(bd[r], off);
            int   oi = __shfl_xor(bi[r], off);
            if (od < bd[r] || (od == bd[r] && oi < bi[r])) { bd[r] = od; bi[r] = oi; }
        }
    }
    if (tcol == 0)
        for (int r = 0; r < 4; ++r)
            enc[row0 + 4 * trow + r] = bi[r];
}

__global__ void out_kernel(const float* __restrict__ lat,
                           const float* __restrict__ emb,
                           const int* __restrict__ gold,
                           const int* __restrict__ enc,
                           float* __restrict__ out,
                           int* __restrict__ counter) {
#pragma clang fp contract(off)
    const int gid  = blockIdx.x * blockDim.x + threadIdx.x;
    const int row  = gid >> 6;
    const int lane = threadIdx.x & 63;
    if (row >= N_ROWS) return;
    const int idx = enc[row];
    const float4* e4 = (const float4*)(emb + (size_t)idx * DIM);
    float4*       q4 = (float4*)(out + (size_t)row * DIM);
    q4[lane]      = e4[lane];
    q4[lane + 64] = e4[lane + 64];
    float r = 0.0f;
    if (lane < 32) {
        const int b = lane >> 3, j = lane & 7;
        const float* ep = emb + (size_t)idx * DIM + b * 128 + j;
        const float* xp = lat + (size_t)row * DIM + b * 128 + j;
        for (int i = 0; i < 16; ++i) {
            float dq = ep[8 * i] - xp[8 * i];
            float s  = dq * dq;
            r = (i == 0) ? s : (r + s);
        }
    }
    for (int m = 1; m <= 16; m <<= 1) {
        float o = __shfl_xor(r, m);
        r = r + o;
    }
    if (lane == 0) {
        float mean = r * (1.0f / 512.0f);
        float v    = mean + 0.25f * mean;
        out[(size_t)N_ROWS * DIM + row]          = v;
        out[(size_t)N_ROWS * DIM + N_ROWS + row] = (float)idx;
        if (gold[row] == idx) atomicAdd(counter, 1);
    }
}

// ---------------------------------------------------------------------------
extern "C" void kernel_launch(void* const* d_in, const int* in_sizes, int n_in,
                              void* d_out, int out_size, void* d_ws, size_t ws_size,
                              hipStream_t stream) {
    (void)in_sizes; (void)n_in; (void)out_size;
    const int*   gold = (const int*)d_in[0];
    const float* lat  = (const float*)d_in[1];
    const float* emb  = (const float*)d_in[3];
    float* out = (float*)d_out;

    const size_t SZ_LATB = (size_t)N_ROWS * DIM * 2;
    const size_t SZ_EMBB = (size_t)KCB * DIM * 2;
    const size_t SZ_TM16 = (size_t)N_ROWS * 512 * 4;   // 64 MB
    const size_t SZ_TM32 = (size_t)N_ROWS * 256 * 4;   // 32 MB
    const size_t SZ_SMALL = (size_t)N_ROWS * 4 + (size_t)KCB * 4 + 256;
    const size_t NEED16 = SZ_LATB + SZ_EMBB + SZ_TM16 + SZ_SMALL;
    const size_t NEED32 = SZ_LATB + SZ_EMBB + SZ_TM32 + SZ_SMALL;

    if (ws_size >= NEED32) {
        const bool g16 = (ws_size >= NEED16);
        const size_t SZ_TM = g16 ? SZ_TM16 : SZ_TM32;
        unsigned char* w8 = (unsigned char*)d_ws;
        unsigned short* latb    = (unsigned short*)w8;
        unsigned short* embb    = (unsigned short*)(w8 + SZ_LATB);
        float*          tilemin = (float*)(w8 + SZ_LATB + SZ_EMBB);
        float*          row_sq  = (float*)(w8 + SZ_LATB + SZ_EMBB + SZ_TM);
        float*          emb_sq  = row_sq + N_ROWS;
        int*            counter = (int*)(emb_sq + KCB);

        hipMemsetAsync(counter, 0, sizeof(int), stream);
        sq_kernel<<<(N_ROWS + KCB) / 8, 256, 0, stream>>>(lat, emb, row_sq, emb_sq);
        cvt_kernel<<<(N_ROWS + KCB) * (DIM / 8) / 256, 256, 0, stream>>>(lat, emb, latb, embb);
        dim3 ggrid(N_ROWS / 256, KCB / (NITER * 128));
        if (g16) {
            gemm_kernel<512><<<ggrid, 512, 0, stream>>>(latb, embb, row_sq, emb_sq, tilemin);
            argmin_out_kernel<512><<<N_ROWS / 4, 256, 0, stream>>>(
                lat, emb, row_sq, emb_sq, tilemin, gold, out, counter);
        } else {
            gemm_kernel<256><<<ggrid, 512, 0, stream>>>(latb, embb, row_sq, emb_sq, tilemin);
            argmin_out_kernel<256><<<N_ROWS / 4, 256, 0, stream>>>(
                lat, emb, row_sq, emb_sq, tilemin, gold, out, counter);
        }
        tail_kernel<<<1, 64, 0, stream>>>(counter, out);
    } else {
        float* row_sq  = (float*)d_ws;
        float* emb_sq  = row_sq + N_ROWS;
        int*   enc     = (int*)(emb_sq + KCB);
        int*   counter = enc + N_ROWS;
        hipMemsetAsync(counter, 0, sizeof(int), stream);
        sq_kernel<<<(N_ROWS + KCB) / 8, 256, 0, stream>>>(lat, emb, row_sq, emb_sq);
        dist_kernel<<<N_ROWS / BM, 256, 0, stream>>>(lat, emb, row_sq, emb_sq, enc);
        out_kernel<<<N_ROWS / 4, 256, 0, stream>>>(lat, emb, gold, enc, out, counter);
        tail_kernel<<<1, 64, 0, stream>>>(counter, out);
    }
}

// Round 4
// 1008.581 us; speedup vs baseline: 4.7082x; 1.3705x over previous
//
#include <hip/hip_runtime.h>
#include <math.h>

#define N_ROWS 32768
#define KCB    8192
#define DIM    512
#define BETA   0.25f
#define MARGIN 3e-4f

typedef __attribute__((ext_vector_type(8))) short  bf16x8;
typedef __attribute__((ext_vector_type(4))) float  f32x4;

// ---------------------------------------------------------------------------
// Kernel 1: ||x||^2 / ||e||^2, numpy-exact pairwise tree, wave-parallel.
// ---------------------------------------------------------------------------
__global__ __launch_bounds__(256) void sq_kernel(
        const float* __restrict__ lat, const float* __restrict__ emb,
        float* __restrict__ row_sq, float* __restrict__ emb_sq) {
#pragma clang fp contract(off)
    const int w    = threadIdx.x >> 6;
    const int lane = threadIdx.x & 63;
    const int half = lane >> 5;
    const int L    = lane & 31;
    const int b    = L >> 3, j = L & 7;
    const int row  = blockIdx.x * 8 + w * 2 + half;
    const int total = N_ROWS + KCB;
    if (row >= total) return;
    const float* p = (row < N_ROWS) ? (lat + (size_t)row * DIM)
                                    : (emb + (size_t)(row - N_ROWS) * DIM);
    const float* q = p + 128 * b + j;
    float a0 = q[0];
    float r  = a0 * a0;
    for (int i = 1; i < 16; ++i) {
        float a = q[8 * i];
        float s = a * a;
        r = r + s;
    }
    r = r + __shfl_xor(r, 1);
    r = r + __shfl_xor(r, 2);
    r = r + __shfl_xor(r, 4);
    r = r + __shfl_xor(r, 8);
    r = r + __shfl_xor(r, 16);
    if (L == 0) {
        if (row < N_ROWS) row_sq[row] = r;
        else              emb_sq[row - N_ROWS] = r;
    }
}

// ---------------------------------------------------------------------------
// Kernel 2: fp32 -> bf16 (RNE) copies.
// ---------------------------------------------------------------------------
__device__ __forceinline__ unsigned short f2bf(float f) {
    unsigned u = __float_as_uint(f);
    return (unsigned short)((u + 0x7FFFu + ((u >> 16) & 1u)) >> 16);
}

__global__ void cvt_kernel(const float* __restrict__ lat,
                           const float* __restrict__ emb,
                           unsigned short* __restrict__ latb,
                           unsigned short* __restrict__ embb) {
    const size_t NL8 = (size_t)N_ROWS * DIM / 8;
    const size_t NE8 = (size_t)KCB * DIM / 8;
    size_t g = (size_t)blockIdx.x * 256 + threadIdx.x;
    const float* src; unsigned short* dst; size_t i;
    if (g < NL8)            { src = lat; dst = latb; i = g; }
    else if (g < NL8 + NE8) { src = emb; dst = embb; i = g - NL8; }
    else return;
    float4 v0 = ((const float4*)src)[2 * i];
    float4 v1 = ((const float4*)src)[2 * i + 1];
    ushort4 o0 = { f2bf(v0.x), f2bf(v0.y), f2bf(v0.z), f2bf(v0.w) };
    ushort4 o1 = { f2bf(v1.x), f2bf(v1.y), f2bf(v1.z), f2bf(v1.w) };
    ((ushort4*)dst)[2 * i]     = o0;
    ((ushort4*)dst)[2 * i + 1] = o1;
}

// ---------------------------------------------------------------------------
// Kernel 3: TRANSPOSED bf16 MFMA GEMM: D[code][latrow]. Block tile =
// 128 codes x 256 rows, 256 threads (2x2 waves of 64 codes x 128 rows,
// 4x8 register tile, acc = 128 AGPRs). Codes on the D-row axis means each
// lane's 4 acc regs span 4 codes -> group-min folds in-register, only 2
// shfls per 16-code group. grid.x = row-tiles (fast) so each XCD's L2
// keeps one 128-code slab hot.
// ---------------------------------------------------------------------------
__device__ __forceinline__ void load16_to_lds(const void* g, void* l) {
    __builtin_amdgcn_global_load_lds(
        (const __attribute__((address_space(1))) unsigned int*)g,
        (__attribute__((address_space(3))) unsigned int*)l, 16, 0, 0);
}

template<int NG>
__global__ __launch_bounds__(256, 2) void gemm_kernel(
        const unsigned short* __restrict__ latb,
        const unsigned short* __restrict__ embb,
        const float* __restrict__ row_sq,
        const float* __restrict__ emb_sq,
        float* __restrict__ tilemin) {
    __shared__ unsigned short Ac[8 * 128 * 8];   // codes  [kg][128][8], 16 KB
    __shared__ unsigned short Br[8 * 256 * 8];   // rows   [kg][256][8], 32 KB

    const int tid   = threadIdx.x;
    const int w     = tid >> 6;
    const int lane  = tid & 63;
    const int q     = lane >> 4;
    const int m16   = lane & 15;
    const int row0  = blockIdx.x * 256;          // latent rows
    const int code0 = blockIdx.y * 128;          // codes
    const int wc    = 64 * (w >> 1);             // wave code base in tile
    const int rbase = 128 * (w & 1);             // wave row base in tile

    f32x4 acc[4][8];
#pragma unroll
    for (int r = 0; r < 4; ++r)
#pragma unroll
        for (int c = 0; c < 8; ++c) acc[r][c] = (f32x4){0.f, 0.f, 0.f, 0.f};

    for (int k0 = 0; k0 < DIM; k0 += 64) {
        // stage 48 chunks of 1 KB: 16 code-chunks + 32 row-chunks
#pragma unroll
        for (int i = 0; i < 12; ++i) {
            int cid = w * 12 + i;
            if (cid < 16) {
                int kg = cid >> 1, h = cid & 1;
                const unsigned short* g = embb +
                    (size_t)(code0 + h * 64 + lane) * DIM + k0 + kg * 8;
                load16_to_lds(g, &Ac[(kg * 128 + h * 64) * 8]);
            } else {
                int c2 = cid - 16, kg = c2 >> 2, h = c2 & 3;
                const unsigned short* g = latb +
                    (size_t)(row0 + h * 64 + lane) * DIM + k0 + kg * 8;
                load16_to_lds(g, &Br[(kg * 256 + h * 64) * 8]);
            }
        }
        __syncthreads();
#pragma unroll
        for (int kk = 0; kk < 2; ++kk) {
            bf16x8 a[4], b[8];
#pragma unroll
            for (int r = 0; r < 4; ++r)
                a[r] = *(const bf16x8*)&Ac[((4 * kk + q) * 128 + wc + 16 * r + m16) * 8];
#pragma unroll
            for (int c = 0; c < 8; ++c)
                b[c] = *(const bf16x8*)&Br[((4 * kk + q) * 256 + rbase + 16 * c + m16) * 8];
#pragma unroll
            for (int r = 0; r < 4; ++r)
#pragma unroll
                for (int c = 0; c < 8; ++c)
                    acc[r][c] = __builtin_amdgcn_mfma_f32_16x16x32_bf16(
                        a[r], b[c], acc[r][c], 0, 0, 0);
        }
        __syncthreads();
    }

    // epilogue: s = (sx + se) - 2*dot ; min over codes per latent row.
    // lane holds codes {code0+wc+16r+4q+reg} for row {row0+rbase+16c+m16}.
    float sxv[8];
#pragma unroll
    for (int c = 0; c < 8; ++c)
        sxv[c] = row_sq[row0 + rbase + 16 * c + m16];
    float sev[4][4];
#pragma unroll
    for (int r = 0; r < 4; ++r)
#pragma unroll
        for (int reg = 0; reg < 4; ++reg)
            sev[r][reg] = emb_sq[code0 + wc + 16 * r + 4 * q + reg];

    if (NG == 512) {
#pragma unroll
        for (int r = 0; r < 4; ++r)
#pragma unroll
            for (int c = 0; c < 8; ++c) {
                float mn = (sxv[c] + sev[r][0]) - 2.0f * acc[r][c][0];
#pragma unroll
                for (int reg = 1; reg < 4; ++reg) {
                    float s = (sxv[c] + sev[r][reg]) - 2.0f * acc[r][c][reg];
                    mn = fminf(mn, s);
                }
                mn = fminf(mn, __shfl_xor(mn, 16));
                mn = fminf(mn, __shfl_xor(mn, 32));
                if (lane < 16)
                    tilemin[(size_t)(row0 + rbase + 16 * c + m16) * 512 +
                            ((code0 + wc + 16 * r) >> 4)] = mn;
            }
    } else {
#pragma unroll
        for (int r2 = 0; r2 < 2; ++r2)
#pragma unroll
            for (int c = 0; c < 8; ++c) {
                float mn = (sxv[c] + sev[2 * r2][0]) - 2.0f * acc[2 * r2][c][0];
#pragma unroll
                for (int reg = 1; reg < 4; ++reg) {
                    float s = (sxv[c] + sev[2 * r2][reg]) - 2.0f * acc[2 * r2][c][reg];
                    mn = fminf(mn, s);
                }
#pragma unroll
                for (int reg = 0; reg < 4; ++reg) {
                    float s = (sxv[c] + sev[2 * r2 + 1][reg]) - 2.0f * acc[2 * r2 + 1][c][reg];
                    mn = fminf(mn, s);
                }
                mn = fminf(mn, __shfl_xor(mn, 16));
                mn = fminf(mn, __shfl_xor(mn, 32));
                if (lane < 16)
                    tilemin[(size_t)(row0 + rbase + 16 * c + m16) * 256 +
                            ((code0 + wc + 32 * r2) >> 5)] = mn;
            }
    }
}

// ---------------------------------------------------------------------------
// Kernel 4 (fused): group-min scan + exact fp32 rescore (R1's bit-identical
// chain) + quantized write + vq_loss + inds + correct count.
// ---------------------------------------------------------------------------
template<int NG>
__global__ __launch_bounds__(256) void argmin_out_kernel(
        const float* __restrict__ lat, const float* __restrict__ emb,
        const float* __restrict__ row_sq, const float* __restrict__ emb_sq,
        const float* __restrict__ tilemin,
        const int* __restrict__ gold,
        float* __restrict__ out, int* __restrict__ counter) {
    constexpr int GS = KCB / NG;
    constexpr int PL = NG / 64;
    __shared__ float xs[4][DIM];
    const int w    = threadIdx.x >> 6;
    const int lane = threadIdx.x & 63;
    const int row  = blockIdx.x * 4 + w;

    {
        const float4* xp = (const float4*)(lat + (size_t)row * DIM);
        ((float4*)xs[w])[lane]      = xp[lane];
        ((float4*)xs[w])[lane + 64] = xp[lane + 64];
    }
    const float sx = row_sq[row];
    const float* xw = xs[w];

    float tm[PL];
    {
        const float4* tb = (const float4*)(tilemin + (size_t)row * NG + lane * PL);
#pragma unroll
        for (int j4 = 0; j4 < PL / 4; ++j4) {
            float4 v = tb[j4];
            tm[4 * j4 + 0] = v.x; tm[4 * j4 + 1] = v.y;
            tm[4 * j4 + 2] = v.z; tm[4 * j4 + 3] = v.w;
        }
    }
    float m = tm[0];
#pragma unroll
    for (int j = 1; j < PL; ++j) m = fminf(m, tm[j]);
#pragma unroll
    for (int off = 1; off < 64; off <<= 1)
        m = fminf(m, __shfl_xor(m, off));
    const float thresh = m + MARGIN;

    float bd = INFINITY;
    int   bi = 0x7fffffff;
#pragma unroll
    for (int j = 0; j < PL; ++j) {
        unsigned long long mask = __ballot(tm[j] <= thresh);
        while (mask) {
            int l = __ffsll(mask) - 1;
            mask &= mask - 1;
            int G = l * PL + j;
            float dvl = INFINITY;
            int   cl  = 0x7fffffff;
            if (lane < GS) {
                int code = G * GS + lane;
                const float* ep = emb + (size_t)code * DIM;
                float acc = 0.0f;
                for (int d = 0; d < DIM; d += 8) {
                    float ev[8], xv[8];
#pragma unroll
                    for (int t = 0; t < 8; ++t) { ev[t] = ep[d + t]; xv[t] = xw[d + t]; }
#pragma unroll
                    for (int t = 0; t < 8; ++t) acc = fmaf(xv[t], ev[t], acc);
                }
                float a = sx + emb_sq[code];
                dvl = a - 2.0f * acc;
                cl  = code;
            }
            if (dvl < bd || (dvl == bd && cl < bi)) { bd = dvl; bi = cl; }
        }
    }
#pragma unroll
    for (int off = 1; off < 64; off <<= 1) {
        float od = __shfl_xor(bd, off);
        int   oi = __shfl_xor(bi, off);
        if (od < bd || (od == bd && oi < bi)) { bd = od; bi = oi; }
    }
    const int idx = bi;

    const float4* e4 = (const float4*)(emb + (size_t)idx * DIM);
    float4*       q4 = (float4*)(out + (size_t)row * DIM);
    q4[lane]      = e4[lane];
    q4[lane + 64] = e4[lane + 64];

    float r = 0.0f;
    if (lane < 32) {
        const int b = lane >> 3, j = lane & 7;
        const float* ep = emb + (size_t)idx * DIM + b * 128 + j;
        const float* xp = xw + b * 128 + j;
        for (int i = 0; i < 16; ++i) {
            float dq = ep[8 * i] - xp[8 * i];
            float s  = dq * dq;
            r = (i == 0) ? s : (r + s);
        }
    }
    for (int mm = 1; mm <= 16; mm <<= 1) {
        float o = __shfl_xor(r, mm);
        r = r + o;
    }
    if (lane == 0) {
        float mean = r * (1.0f / 512.0f);
        float v    = mean + 0.25f * mean;
        out[(size_t)N_ROWS * DIM + row]          = v;
        out[(size_t)N_ROWS * DIM + N_ROWS + row] = (float)idx;
        if (gold[row] == idx) atomicAdd(counter, 1);
    }
}

__global__ void tail_kernel(const int* __restrict__ counter,
                            float* __restrict__ out) {
    if (threadIdx.x == 0 && blockIdx.x == 0) {
        const size_t off = (size_t)N_ROWS * DIM + 2 * (size_t)N_ROWS;
        out[off]     = (float)(*counter);
        out[off + 1] = (float)N_ROWS;
    }
}

// ---------------------------------------------------------------------------
// Fallback path (tiny ws): R1 fp32 dist + separate out kernel.
// ---------------------------------------------------------------------------
#define BM 64
#define BK 128
#define BD 32
__global__ __launch_bounds__(256) void dist_kernel(
        const float* __restrict__ lat, const float* __restrict__ emb,
        const float* __restrict__ row_sq, const float* __restrict__ emb_sq,
        int* __restrict__ enc) {
    __shared__ float xsh[BD][BM];
    __shared__ float esh[BD][BK];
    const int tid  = threadIdx.x;
    const int trow = tid >> 4;
    const int tcol = tid & 15;
    const int row0 = blockIdx.x * BM;
    float bd[4]; int bi[4];
    for (int i = 0; i < 4; ++i) { bd[i] = INFINITY; bi[i] = 0; }
    float sx[4];
    for (int i = 0; i < 4; ++i) sx[i] = row_sq[row0 + 4 * trow + i];
    for (int kt = 0; kt < KCB; kt += BK) {
        float acc[4][8] = {};
        for (int d0 = 0; d0 < DIM; d0 += BD) {
            for (int f = tid; f < BM * BD / 4; f += 256) {
                int r = f >> 3, c4 = f & 7;
                float4 v = *(const float4*)(lat + (size_t)(row0 + r) * DIM + d0 + 4 * c4);
                xsh[4 * c4 + 0][r] = v.x; xsh[4 * c4 + 1][r] = v.y;
                xsh[4 * c4 + 2][r] = v.z; xsh[4 * c4 + 3][r] = v.w;
            }
            for (int f = tid; f < BK * BD / 4; f += 256) {
                int r = f >> 3, c4 = f & 7;
                float4 v = *(const float4*)(emb + (size_t)(kt + r) * DIM + d0 + 4 * c4);
                esh[4 * c4 + 0][r] = v.x; esh[4 * c4 + 1][r] = v.y;
                esh[4 * c4 + 2][r] = v.z; esh[4 * c4 + 3][r] = v.w;
            }
            __syncthreads();
            for (int dd = 0; dd < BD; ++dd) {
                float4 xv  = *(const float4*)&xsh[dd][4 * trow];
                float4 ev0 = *(const float4*)&esh[dd][8 * tcol];
                float4 ev1 = *(const float4*)&esh[dd][8 * tcol + 4];
                float xr[4] = { xv.x, xv.y, xv.z, xv.w };
                float ec[8] = { ev0.x, ev0.y, ev0.z, ev0.w, ev1.x, ev1.y, ev1.z, ev1.w };
                for (int r = 0; r < 4; ++r)
                    for (int c = 0; c < 8; ++c)
                        acc[r][c] = fmaf(xr[r], ec[c], acc[r][c]);
            }
            __syncthreads();
        }
        for (int c = 0; c < 8; ++c) {
            int   code = kt + 8 * tcol + c;
            float se   = emb_sq[code];
            for (int r = 0; r < 4; ++r) {
                float a  = sx[r] + se;
                float dv = a - 2.0f * acc[r][c];
                if (dv < bd[r]) { bd[r] = dv; bi[r] = code; }
            }
        }
    }
    for (int off = 1; off < 16; off <<= 1) {
        for (int r = 0; r < 4; ++r) {
            float od = __shfl_xor(bd[r], off);
            int   oi = __shfl_xor(bi[r], off);
            if (od < bd[r] || (od == bd[r] && oi < bi[r])) { bd[r] = od; bi[r] = oi; }
        }
    }
    if (tcol == 0)
        for (int r = 0; r < 4; ++r)
            enc[row0 + 4 * trow + r] = bi[r];
}

__global__ void out_kernel(const float* __restrict__ lat,
                           const float* __restrict__ emb,
                           const int* __restrict__ gold,
                           const int* __restrict__ enc,
                           float* __restrict__ out,
                           int* __restrict__ counter) {
#pragma clang fp contract(off)
    const int gid  = blockIdx.x * blockDim.x + threadIdx.x;
    const int row  = gid >> 6;
    const int lane = threadIdx.x & 63;
    if (row >= N_ROWS) return;
    const int idx = enc[row];
    const float4* e4 = (const float4*)(emb + (size_t)idx * DIM);
    float4*       q4 = (float4*)(out + (size_t)row * DIM);
    q4[lane]      = e4[lane];
    q4[lane + 64] = e4[lane + 64];
    float r = 0.0f;
    if (lane < 32) {
        const int b = lane >> 3, j = lane & 7;
        const float* ep = emb + (size_t)idx * DIM + b * 128 + j;
        const float* xp = lat + (size_t)row * DIM + b * 128 + j;
        for (int i = 0; i < 16; ++i) {
            float dq = ep[8 * i] - xp[8 * i];
            float s  = dq * dq;
            r = (i == 0) ? s : (r + s);
        }
    }
    for (int m = 1; m <= 16; m <<= 1) {
        float o = __shfl_xor(r, m);
        r = r + o;
    }
    if (lane == 0) {
        float mean = r * (1.0f / 512.0f);
        float v    = mean + 0.25f * mean;
        out[(size_t)N_ROWS * DIM + row]          = v;
        out[(size_t)N_ROWS * DIM + N_ROWS + row] = (float)idx;
        if (gold[row] == idx) atomicAdd(counter, 1);
    }
}

// ---------------------------------------------------------------------------
extern "C" void kernel_launch(void* const* d_in, const int* in_sizes, int n_in,
                              void* d_out, int out_size, void* d_ws, size_t ws_size,
                              hipStream_t stream) {
    (void)in_sizes; (void)n_in; (void)out_size;
    const int*   gold = (const int*)d_in[0];
    const float* lat  = (const float*)d_in[1];
    const float* emb  = (const float*)d_in[3];
    float* out = (float*)d_out;

    const size_t SZ_LATB = (size_t)N_ROWS * DIM * 2;
    const size_t SZ_EMBB = (size_t)KCB * DIM * 2;
    const size_t SZ_TM16 = (size_t)N_ROWS * 512 * 4;
    const size_t SZ_TM32 = (size_t)N_ROWS * 256 * 4;
    const size_t SZ_SMALL = (size_t)N_ROWS * 4 + (size_t)KCB * 4 + 256;
    const size_t NEED16 = SZ_LATB + SZ_EMBB + SZ_TM16 + SZ_SMALL;
    const size_t NEED32 = SZ_LATB + SZ_EMBB + SZ_TM32 + SZ_SMALL;

    if (ws_size >= NEED32) {
        const bool g16 = (ws_size >= NEED16);
        const size_t SZ_TM = g16 ? SZ_TM16 : SZ_TM32;
        unsigned char* w8 = (unsigned char*)d_ws;
        unsigned short* latb    = (unsigned short*)w8;
        unsigned short* embb    = (unsigned short*)(w8 + SZ_LATB);
        float*          tilemin = (float*)(w8 + SZ_LATB + SZ_EMBB);
        float*          row_sq  = (float*)(w8 + SZ_LATB + SZ_EMBB + SZ_TM);
        float*          emb_sq  = row_sq + N_ROWS;
        int*            counter = (int*)(emb_sq + KCB);

        hipMemsetAsync(counter, 0, sizeof(int), stream);
        sq_kernel<<<(N_ROWS + KCB) / 8, 256, 0, stream>>>(lat, emb, row_sq, emb_sq);
        cvt_kernel<<<(N_ROWS + KCB) * (DIM / 8) / 256, 256, 0, stream>>>(lat, emb, latb, embb);
        dim3 ggrid(N_ROWS / 256, KCB / 128);   // x = row-tiles (fast-varying)
        if (g16) {
            gemm_kernel<512><<<ggrid, 256, 0, stream>>>(latb, embb, row_sq, emb_sq, tilemin);
            argmin_out_kernel<512><<<N_ROWS / 4, 256, 0, stream>>>(
                lat, emb, row_sq, emb_sq, tilemin, gold, out, counter);
        } else {
            gemm_kernel<256><<<ggrid, 256, 0, stream>>>(latb, embb, row_sq, emb_sq, tilemin);
            argmin_out_kernel<256><<<N_ROWS / 4, 256, 0, stream>>>(
                lat, emb, row_sq, emb_sq, tilemin, gold, out, counter);
        }
        tail_kernel<<<1, 64, 0, stream>>>(counter, out);
    } else {
        float* row_sq  = (float*)d_ws;
        float* emb_sq  = row_sq + N_ROWS;
        int*   enc     = (int*)(emb_sq + KCB);
        int*   counter = enc + N_ROWS;
        hipMemsetAsync(counter, 0, sizeof(int), stream);
        sq_kernel<<<(N_ROWS + KCB) / 8, 256, 0, stream>>>(lat, emb, row_sq, emb_sq);
        dist_kernel<<<N_ROWS / BM, 256, 0, stream>>>(lat, emb, row_sq, emb_sq, enc);
        out_kernel<<<N_ROWS / 4, 256, 0, stream>>>(lat, emb, gold, enc, out, counter);
        tail_kernel<<<1, 64, 0, stream>>>(counter, out);
    }
}

// Round 5
// 811.263 us; speedup vs baseline: 5.8534x; 1.2432x over previous
//
#include <hip/hip_runtime.h>
#include <math.h>

#define N_ROWS 32768
#define KCB    8192
#define DIM    512
#define BETA   0.25f
#define MARGIN 2e-3f
#define CAND_CAP 256

typedef __attribute__((ext_vector_type(4))) float  f32x4;

// ---------------------------------------------------------------------------
// Kernel 1: ||x||^2 / ||e||^2, numpy-exact pairwise tree, wave-parallel.
// ---------------------------------------------------------------------------
__global__ __launch_bounds__(256) void sq_kernel(
        const float* __restrict__ lat, const float* __restrict__ emb,
        float* __restrict__ row_sq, float* __restrict__ emb_sq) {
#pragma clang fp contract(off)
    const int w    = threadIdx.x >> 6;
    const int lane = threadIdx.x & 63;
    const int half = lane >> 5;
    const int L    = lane & 31;
    const int b    = L >> 3, j = L & 7;
    const int row  = blockIdx.x * 8 + w * 2 + half;
    const int total = N_ROWS + KCB;
    if (row >= total) return;
    const float* p = (row < N_ROWS) ? (lat + (size_t)row * DIM)
                                    : (emb + (size_t)(row - N_ROWS) * DIM);
    const float* q = p + 128 * b + j;
    float a0 = q[0];
    float r  = a0 * a0;
    for (int i = 1; i < 16; ++i) {
        float a = q[8 * i];
        float s = a * a;
        r = r + s;
    }
    r = r + __shfl_xor(r, 1);
    r = r + __shfl_xor(r, 2);
    r = r + __shfl_xor(r, 4);
    r = r + __shfl_xor(r, 8);
    r = r + __shfl_xor(r, 16);
    if (L == 0) {
        if (row < N_ROWS) row_sq[row] = r;
        else              emb_sq[row - N_ROWS] = r;
    }
}

// ---------------------------------------------------------------------------
// Kernel 2: fp32 -> fp8 e4m3 (OCP) copies. emb is pre-scaled by 2^13 (exact)
// so its U(-1/8192,1/8192) values land in U(-1,1); the gemm epilogue undoes
// the scale with *2^-12 on 2*dot. Packed HW convert, 8 B/lane stores.
// ---------------------------------------------------------------------------
__global__ void cvt_kernel(const float* __restrict__ lat,
                           const float* __restrict__ emb,
                           unsigned char* __restrict__ latq,
                           unsigned char* __restrict__ embq) {
    const size_t NL8 = (size_t)N_ROWS * DIM / 8;
    const size_t NE8 = (size_t)KCB * DIM / 8;
    size_t g = (size_t)blockIdx.x * 256 + threadIdx.x;
    const float* src; unsigned char* dst; size_t i; float sc;
    if (g < NL8)            { src = lat; dst = latq; i = g;       sc = 1.0f; }
    else if (g < NL8 + NE8) { src = emb; dst = embq; i = g - NL8; sc = 8192.0f; }
    else return;
    float4 v0 = ((const float4*)src)[2 * i];
    float4 v1 = ((const float4*)src)[2 * i + 1];
    int lo = __builtin_amdgcn_cvt_pk_fp8_f32(v0.x * sc, v0.y * sc, 0,  false);
    lo     = __builtin_amdgcn_cvt_pk_fp8_f32(v0.z * sc, v0.w * sc, lo, true);
    int hi = __builtin_amdgcn_cvt_pk_fp8_f32(v1.x * sc, v1.y * sc, 0,  false);
    hi     = __builtin_amdgcn_cvt_pk_fp8_f32(v1.z * sc, v1.w * sc, hi, true);
    ((int2*)dst)[i] = make_int2(lo, hi);
}

// ---------------------------------------------------------------------------
// Kernel 3: fp8 MFMA GEMM (transposed: D[code][latrow]), 128 codes x 256
// rows per block, 256 threads. LDS layout [k16grp][row][16B] so the 16-B
// global_load_lds chunk covers 16 consecutive k. Epilogue: per-(row, group)
// min + 16/32-bit candidate bitmap (codes within MARGIN of group min).
// ---------------------------------------------------------------------------
__device__ __forceinline__ void load16_to_lds(const void* g, void* l) {
    __builtin_amdgcn_global_load_lds(
        (const __attribute__((address_space(1))) unsigned int*)g,
        (__attribute__((address_space(3))) unsigned int*)l, 16, 0, 0);
}

template<int NG>
__global__ __launch_bounds__(256, 2) void gemm_kernel(
        const unsigned char* __restrict__ latq,
        const unsigned char* __restrict__ embq,
        const float* __restrict__ row_sq,
        const float* __restrict__ emb_sq,
        float* __restrict__ tilemin,
        void* __restrict__ bmp_raw) {
    __shared__ unsigned char Ac[4 * 128 * 16];   // codes [p][128][16B], 8 KB
    __shared__ unsigned char Br[4 * 256 * 16];   // rows  [p][256][16B], 16 KB

    const int tid   = threadIdx.x;
    const int w     = tid >> 6;
    const int lane  = tid & 63;
    const int q     = lane >> 4;
    const int m16   = lane & 15;
    const int row0  = blockIdx.x * 256;
    const int code0 = blockIdx.y * 128;
    const int wc    = 64 * (w >> 1);
    const int rbase = 128 * (w & 1);

    f32x4 acc[4][8];
#pragma unroll
    for (int r = 0; r < 4; ++r)
#pragma unroll
        for (int c = 0; c < 8; ++c) acc[r][c] = (f32x4){0.f, 0.f, 0.f, 0.f};

    for (int k0 = 0; k0 < DIM; k0 += 64) {
        // 24 chunks of 1 KB: 8 code-chunks (p,h2) + 16 row-chunks (p,h4)
#pragma unroll
        for (int i = 0; i < 6; ++i) {
            int cid = w * 6 + i;
            if (cid < 8) {
                int p = cid >> 1, h = cid & 1;
                const unsigned char* g = embq +
                    (size_t)(code0 + h * 64 + lane) * DIM + k0 + p * 16;
                load16_to_lds(g, &Ac[(p * 128 + h * 64) * 16]);
            } else {
                int c2 = cid - 8, p = c2 >> 2, h = c2 & 3;
                const unsigned char* g = latq +
                    (size_t)(row0 + h * 64 + lane) * DIM + k0 + p * 16;
                load16_to_lds(g, &Br[(p * 256 + h * 64) * 16]);
            }
        }
        __syncthreads();
#pragma unroll
        for (int kk = 0; kk < 2; ++kk) {
            long a[4], b[8];
            const int kg = kk * 4 + q;          // 8-k group for this lane
            const int p  = kg >> 1, hf = (kg & 1) * 8;
#pragma unroll
            for (int r = 0; r < 4; ++r)
                a[r] = *(const long*)&Ac[(p * 128 + wc + 16 * r + m16) * 16 + hf];
#pragma unroll
            for (int c = 0; c < 8; ++c)
                b[c] = *(const long*)&Br[(p * 256 + rbase + 16 * c + m16) * 16 + hf];
#pragma unroll
            for (int r = 0; r < 4; ++r)
#pragma unroll
                for (int c = 0; c < 8; ++c)
                    acc[r][c] = __builtin_amdgcn_mfma_f32_16x16x32_fp8_fp8(
                        a[r], b[c], acc[r][c], 0, 0, 0);
        }
        __syncthreads();
    }

    // epilogue: s = (sx+se) - 2^-12 * dotq ; group min + candidate bitmap
    float sxv[8];
#pragma unroll
    for (int c = 0; c < 8; ++c)
        sxv[c] = row_sq[row0 + rbase + 16 * c + m16];
    float sev[4][4];
#pragma unroll
    for (int r = 0; r < 4; ++r)
#pragma unroll
        for (int reg = 0; reg < 4; ++reg)
            sev[r][reg] = emb_sq[code0 + wc + 16 * r + 4 * q + reg];

    const float inv = 1.0f / 4096.0f;   // 2 * 2^-13
    if (NG == 512) {
        unsigned short* bmp = (unsigned short*)bmp_raw;
#pragma unroll
        for (int r = 0; r < 4; ++r)
#pragma unroll
            for (int c = 0; c < 8; ++c) {
                float s[4];
#pragma unroll
                for (int reg = 0; reg < 4; ++reg)
                    s[reg] = (sxv[c] + sev[r][reg]) - acc[r][c][reg] * inv;
                float mn = fminf(fminf(s[0], s[1]), fminf(s[2], s[3]));
                mn = fminf(mn, __shfl_xor(mn, 16));
                mn = fminf(mn, __shfl_xor(mn, 32));
                unsigned bm = 0;
#pragma unroll
                for (int reg = 0; reg < 4; ++reg) {
                    unsigned long long bal = __ballot(s[reg] <= mn + MARGIN);
#pragma unroll
                    for (int qq = 0; qq < 4; ++qq)
                        bm |= ((unsigned)((bal >> (qq * 16 + m16)) & 1ull))
                              << (4 * qq + reg);
                }
                if (lane < 16) {
                    int grow = row0 + rbase + 16 * c + m16;
                    int gcol = ((code0 + wc) >> 4) + r;
                    tilemin[(size_t)grow * 512 + gcol] = mn;
                    bmp[(size_t)grow * 512 + gcol] = (unsigned short)bm;
                }
            }
    } else {
        unsigned* bmp = (unsigned*)bmp_raw;
#pragma unroll
        for (int r2 = 0; r2 < 2; ++r2)
#pragma unroll
            for (int c = 0; c < 8; ++c) {
                float s[2][4];
#pragma unroll
                for (int rr = 0; rr < 2; ++rr)
#pragma unroll
                    for (int reg = 0; reg < 4; ++reg)
                        s[rr][reg] = (sxv[c] + sev[2 * r2 + rr][reg])
                                     - acc[2 * r2 + rr][c][reg] * inv;
                float mn = fminf(fminf(s[0][0], s[0][1]), fminf(s[0][2], s[0][3]));
#pragma unroll
                for (int reg = 0; reg < 4; ++reg) mn = fminf(mn, s[1][reg]);
                mn = fminf(mn, __shfl_xor(mn, 16));
                mn = fminf(mn, __shfl_xor(mn, 32));
                unsigned bm = 0;
#pragma unroll
                for (int rr = 0; rr < 2; ++rr)
#pragma unroll
                    for (int reg = 0; reg < 4; ++reg) {
                        unsigned long long bal = __ballot(s[rr][reg] <= mn + MARGIN);
#pragma unroll
                        for (int qq = 0; qq < 4; ++qq)
                            bm |= ((unsigned)((bal >> (qq * 16 + m16)) & 1ull))
                                  << (16 * rr + 4 * qq + reg);
                    }
                if (lane < 16) {
                    int grow = row0 + rbase + 16 * c + m16;
                    int gcol = ((code0 + wc) >> 5) + r2;
                    tilemin[(size_t)grow * 256 + gcol] = mn;
                    bmp[(size_t)grow * 256 + gcol] = bm;
                }
            }
    }
}

// ---------------------------------------------------------------------------
// Kernel 4 (fused): global min of group mins -> flagged groups -> candidate
// codes from bitmaps -> exact fp32 rescore (one code per lane, R1's
// bit-identical sequential-fmaf chain) -> outputs.
// ---------------------------------------------------------------------------
template<int NG>
__global__ __launch_bounds__(256) void argmin_out_kernel(
        const float* __restrict__ lat, const float* __restrict__ emb,
        const float* __restrict__ row_sq, const float* __restrict__ emb_sq,
        const float* __restrict__ tilemin, const void* __restrict__ bmp_raw,
        const int* __restrict__ gold,
        float* __restrict__ out, int* __restrict__ counter) {
    constexpr int GS = KCB / NG;
    constexpr int PL = NG / 64;
    __shared__ float xs[4][DIM];
    __shared__ int   s_cnt[4];
    __shared__ int   s_list[4][CAND_CAP];
    const int w    = threadIdx.x >> 6;
    const int lane = threadIdx.x & 63;
    const int row  = blockIdx.x * 4 + w;

    {
        const float4* xp = (const float4*)(lat + (size_t)row * DIM);
        ((float4*)xs[w])[lane]      = xp[lane];
        ((float4*)xs[w])[lane + 64] = xp[lane + 64];
    }
    const float sx = row_sq[row];
    const float* xw = xs[w];

    float tm[PL];
    {
        const float4* tb = (const float4*)(tilemin + (size_t)row * NG + lane * PL);
#pragma unroll
        for (int j4 = 0; j4 < PL / 4; ++j4) {
            float4 v = tb[j4];
            tm[4 * j4 + 0] = v.x; tm[4 * j4 + 1] = v.y;
            tm[4 * j4 + 2] = v.z; tm[4 * j4 + 3] = v.w;
        }
    }
    float m = tm[0];
#pragma unroll
    for (int j = 1; j < PL; ++j) m = fminf(m, tm[j]);
#pragma unroll
    for (int off = 1; off < 64; off <<= 1)
        m = fminf(m, __shfl_xor(m, off));
    const float thresh = m + MARGIN;

    if (lane == 0) s_cnt[w] = 0;
    __syncthreads();
#pragma unroll
    for (int j = 0; j < PL; ++j) {
        if (tm[j] <= thresh) {
            int g = lane * PL + j;
            unsigned bm;
            if (NG == 512)
                bm = ((const unsigned short*)bmp_raw)[(size_t)row * 512 + g];
            else
                bm = ((const unsigned*)bmp_raw)[(size_t)row * 256 + g];
            while (bm) {
                int b = __ffs(bm) - 1;
                bm &= bm - 1;
                int pos = atomicAdd(&s_cnt[w], 1);
                if (pos < CAND_CAP) s_list[w][pos] = g * GS + b;
            }
        }
    }
    __syncthreads();
    const int cnt = min(s_cnt[w], CAND_CAP);

    float bd = INFINITY;
    int   bi = 0x7fffffff;
    for (int base = 0; base < cnt; base += 64) {
        int ci = base + lane;
        float dvl = INFINITY;
        int   cl  = 0x7fffffff;
        if (ci < cnt) {
            int code = s_list[w][ci];
            const float* ep = emb + (size_t)code * DIM;
            float acc = 0.0f;
            for (int d = 0; d < DIM; d += 8) {
                float ev[8], xv[8];
#pragma unroll
                for (int t = 0; t < 8; ++t) { ev[t] = ep[d + t]; xv[t] = xw[d + t]; }
#pragma unroll
                for (int t = 0; t < 8; ++t) acc = fmaf(xv[t], ev[t], acc);
            }
            float a = sx + emb_sq[code];
            dvl = a - 2.0f * acc;
            cl  = code;
        }
        if (dvl < bd || (dvl == bd && cl < bi)) { bd = dvl; bi = cl; }
    }
#pragma unroll
    for (int off = 1; off < 64; off <<= 1) {
        float od = __shfl_xor(bd, off);
        int   oi = __shfl_xor(bi, off);
        if (od < bd || (od == bd && oi < bi)) { bd = od; bi = oi; }
    }
    const int idx = bi;

    const float4* e4 = (const float4*)(emb + (size_t)idx * DIM);
    float4*       q4 = (float4*)(out + (size_t)row * DIM);
    q4[lane]      = e4[lane];
    q4[lane + 64] = e4[lane + 64];

    float r = 0.0f;
    if (lane < 32) {
        const int b = lane >> 3, j = lane & 7;
        const float* ep = emb + (size_t)idx * DIM + b * 128 + j;
        const float* xp = xw + b * 128 + j;
        for (int i = 0; i < 16; ++i) {
            float dq = ep[8 * i] - xp[8 * i];
            float s  = dq * dq;
            r = (i == 0) ? s : (r + s);
        }
    }
    for (int mm = 1; mm <= 16; mm <<= 1) {
        float o = __shfl_xor(r, mm);
        r = r + o;
    }
    if (lane == 0) {
        float mean = r * (1.0f / 512.0f);
        float v    = mean + 0.25f * mean;
        out[(size_t)N_ROWS * DIM + row]          = v;
        out[(size_t)N_ROWS * DIM + N_ROWS + row] = (float)idx;
        if (gold[row] == idx) atomicAdd(counter, 1);
    }
}

__global__ void tail_kernel(const int* __restrict__ counter,
                            float* __restrict__ out) {
    if (threadIdx.x == 0 && blockIdx.x == 0) {
        const size_t off = (size_t)N_ROWS * DIM + 2 * (size_t)N_ROWS;
        out[off]     = (float)(*counter);
        out[off + 1] = (float)N_ROWS;
    }
}

// ---------------------------------------------------------------------------
// Fallback path (tiny ws): R1 fp32 dist + separate out kernel.
// ---------------------------------------------------------------------------
#define BM 64
#define BK 128
#define BD 32
__global__ __launch_bounds__(256) void dist_kernel(
        const float* __restrict__ lat, const float* __restrict__ emb,
        const float* __restrict__ row_sq, const float* __restrict__ emb_sq,
        int* __restrict__ enc) {
    __shared__ float xsh[BD][BM];
    __shared__ float esh[BD][BK];
    const int tid  = threadIdx.x;
    const int trow = tid >> 4;
    const int tcol = tid & 15;
    const int row0 = blockIdx.x * BM;
    float bd[4]; int bi[4];
    for (int i = 0; i < 4; ++i) { bd[i] = INFINITY; bi[i] = 0; }
    float sx[4];
    for (int i = 0; i < 4; ++i) sx[i] = row_sq[row0 + 4 * trow + i];
    for (int kt = 0; kt < KCB; kt += BK) {
        float acc[4][8] = {};
        for (int d0 = 0; d0 < DIM; d0 += BD) {
            for (int f = tid; f < BM * BD / 4; f += 256) {
                int r = f >> 3, c4 = f & 7;
                float4 v = *(const float4*)(lat + (size_t)(row0 + r) * DIM + d0 + 4 * c4);
                xsh[4 * c4 + 0][r] = v.x; xsh[4 * c4 + 1][r] = v.y;
                xsh[4 * c4 + 2][r] = v.z; xsh[4 * c4 + 3][r] = v.w;
            }
            for (int f = tid; f < BK * BD / 4; f += 256) {
                int r = f >> 3, c4 = f & 7;
                float4 v = *(const float4*)(emb + (size_t)(kt + r) * DIM + d0 + 4 * c4);
                esh[4 * c4 + 0][r] = v.x; esh[4 * c4 + 1][r] = v.y;
                esh[4 * c4 + 2][r] = v.z; esh[4 * c4 + 3][r] = v.w;
            }
            __syncthreads();
            for (int dd = 0; dd < BD; ++dd) {
                float4 xv  = *(const float4*)&xsh[dd][4 * trow];
                float4 ev0 = *(const float4*)&esh[dd][8 * tcol];
                float4 ev1 = *(const float4*)&esh[dd][8 * tcol + 4];
                float xr[4] = { xv.x, xv.y, xv.z, xv.w };
                float ec[8] = { ev0.x, ev0.y, ev0.z, ev0.w, ev1.x, ev1.y, ev1.z, ev1.w };
                for (int r = 0; r < 4; ++r)
                    for (int c = 0; c < 8; ++c)
                        acc[r][c] = fmaf(xr[r], ec[c], acc[r][c]);
            }
            __syncthreads();
        }
        for (int c = 0; c < 8; ++c) {
            int   code = kt + 8 * tcol + c;
            float se   = emb_sq[code];
            for (int r = 0; r < 4; ++r) {
                float a  = sx[r] + se;
                float dv = a - 2.0f * acc[r][c];
                if (dv < bd[r]) { bd[r] = dv; bi[r] = code; }
            }
        }
    }
    for (int off = 1; off < 16; off <<= 1) {
        for (int r = 0; r < 4; ++r) {
            float od = __shfl_xor(bd[r], off);
            int   oi = __shfl_xor(bi[r], off);
            if (od < bd[r] || (od == bd[r] && oi < bi[r])) { bd[r] = od; bi[r] = oi; }
        }
    }
    if (tcol == 0)
        for (int r = 0; r < 4; ++r)
            enc[row0 + 4 * trow + r] = bi[r];
}

__global__ void out_kernel(const float* __restrict__ lat,
                           const float* __restrict__ emb,
                           const int* __restrict__ gold,
                           const int* __restrict__ enc,
                           float* __restrict__ out,
                           int* __restrict__ counter) {
#pragma clang fp contract(off)
    const int gid  = blockIdx.x * blockDim.x + threadIdx.x;
    const int row  = gid >> 6;
    const int lane = threadIdx.x & 63;
    if (row >= N_ROWS) return;
    const int idx = enc[row];
    const float4* e4 = (const float4*)(emb + (size_t)idx * DIM);
    float4*       q4 = (float4*)(out + (size_t)row * DIM);
    q4[lane]      = e4[lane];
    q4[lane + 64] = e4[lane + 64];
    float r = 0.0f;
    if (lane < 32) {
        const int b = lane >> 3, j = lane & 7;
        const float* ep = emb + (size_t)idx * DIM + b * 128 + j;
        const float* xp = lat + (size_t)row * DIM + b * 128 + j;
        for (int i = 0; i < 16; ++i) {
            float dq = ep[8 * i] - xp[8 * i];
            float s  = dq * dq;
            r = (i == 0) ? s : (r + s);
        }
    }
    for (int m = 1; m <= 16; m <<= 1) {
        float o = __shfl_xor(r, m);
        r = r + o;
    }
    if (lane == 0) {
        float mean = r * (1.0f / 512.0f);
        float v    = mean + 0.25f * mean;
        out[(size_t)N_ROWS * DIM + row]          = v;
        out[(size_t)N_ROWS * DIM + N_ROWS + row] = (float)idx;
        if (gold[row] == idx) atomicAdd(counter, 1);
    }
}

// ---------------------------------------------------------------------------
extern "C" void kernel_launch(void* const* d_in, const int* in_sizes, int n_in,
                              void* d_out, int out_size, void* d_ws, size_t ws_size,
                              hipStream_t stream) {
    (void)in_sizes; (void)n_in; (void)out_size;
    const int*   gold = (const int*)d_in[0];
    const float* lat  = (const float*)d_in[1];
    const float* emb  = (const float*)d_in[3];
    float* out = (float*)d_out;

    const size_t SZ_LATQ  = (size_t)N_ROWS * DIM;        // 16 MB
    const size_t SZ_EMBQ  = (size_t)KCB * DIM;           //  4 MB
    const size_t SZ_TM512 = (size_t)N_ROWS * 512 * 4;    // 64 MB
    const size_t SZ_BM512 = (size_t)N_ROWS * 512 * 2;    // 32 MB
    const size_t SZ_TM256 = (size_t)N_ROWS * 256 * 4;    // 32 MB
    const size_t SZ_BM256 = (size_t)N_ROWS * 256 * 4;    // 32 MB
    const size_t SZ_SMALL = (size_t)N_ROWS * 4 + (size_t)KCB * 4 + 256;
    const size_t NEED512 = SZ_LATQ + SZ_EMBQ + SZ_TM512 + SZ_BM512 + SZ_SMALL;
    const size_t NEED256 = SZ_LATQ + SZ_EMBQ + SZ_TM256 + SZ_BM256 + SZ_SMALL;

    if (ws_size >= NEED256) {
        const bool g16 = (ws_size >= NEED512);
        const size_t SZ_TM = g16 ? SZ_TM512 : SZ_TM256;
        const size_t SZ_BM = g16 ? SZ_BM512 : SZ_BM256;
        unsigned char* w8 = (unsigned char*)d_ws;
        unsigned char* latq    = w8;
        unsigned char* embq    = w8 + SZ_LATQ;
        float*         tilemin = (float*)(w8 + SZ_LATQ + SZ_EMBQ);
        void*          bmp     = (void*)(w8 + SZ_LATQ + SZ_EMBQ + SZ_TM);
        float*         row_sq  = (float*)(w8 + SZ_LATQ + SZ_EMBQ + SZ_TM + SZ_BM);
        float*         emb_sq  = row_sq + N_ROWS;
        int*           counter = (int*)(emb_sq + KCB);

        hipMemsetAsync(counter, 0, sizeof(int), stream);
        sq_kernel<<<(N_ROWS + KCB) / 8, 256, 0, stream>>>(lat, emb, row_sq, emb_sq);
        cvt_kernel<<<(N_ROWS + KCB) * (DIM / 8) / 256, 256, 0, stream>>>(lat, emb, latq, embq);
        dim3 ggrid(N_ROWS / 256, KCB / 128);
        if (g16) {
            gemm_kernel<512><<<ggrid, 256, 0, stream>>>(latq, embq, row_sq, emb_sq, tilemin, bmp);
            argmin_out_kernel<512><<<N_ROWS / 4, 256, 0, stream>>>(
                lat, emb, row_sq, emb_sq, tilemin, bmp, gold, out, counter);
        } else {
            gemm_kernel<256><<<ggrid, 256, 0, stream>>>(latq, embq, row_sq, emb_sq, tilemin, bmp);
            argmin_out_kernel<256><<<N_ROWS / 4, 256, 0, stream>>>(
                lat, emb, row_sq, emb_sq, tilemin, bmp, gold, out, counter);
        }
        tail_kernel<<<1, 64, 0, stream>>>(counter, out);
    } else {
        float* row_sq  = (float*)d_ws;
        float* emb_sq  = row_sq + N_ROWS;
        int*   enc     = (int*)(emb_sq + KCB);
        int*   counter = enc + N_ROWS;
        hipMemsetAsync(counter, 0, sizeof(int), stream);
        sq_kernel<<<(N_ROWS + KCB) / 8, 256, 0, stream>>>(lat, emb, row_sq, emb_sq);
        dist_kernel<<<N_ROWS / BM, 256, 0, stream>>>(lat, emb, row_sq, emb_sq, enc);
        out_kernel<<<N_ROWS / 4, 256, 0, stream>>>(lat, emb, gold, enc, out, counter);
        tail_kernel<<<1, 64, 0, stream>>>(counter, out);
    }
}

// Round 6
// 684.357 us; speedup vs baseline: 6.9388x; 1.1854x over previous
//
#include <hip/hip_runtime.h>
#include <math.h>

#define N_ROWS 32768
#define KCB    8192
#define DIM    512
#define BETA   0.25f
#define MARGIN 2e-3f
#define CAND_CAP 256
#define NITER  4

typedef __attribute__((ext_vector_type(4))) float  f32x4;

// ---------------------------------------------------------------------------
// Kernel 1: ||x||^2 / ||e||^2, numpy-exact pairwise tree, wave-parallel.
// ---------------------------------------------------------------------------
__global__ __launch_bounds__(256) void sq_kernel(
        const float* __restrict__ lat, const float* __restrict__ emb,
        float* __restrict__ row_sq, float* __restrict__ emb_sq) {
#pragma clang fp contract(off)
    const int w    = threadIdx.x >> 6;
    const int lane = threadIdx.x & 63;
    const int half = lane >> 5;
    const int L    = lane & 31;
    const int b    = L >> 3, j = L & 7;
    const int row  = blockIdx.x * 8 + w * 2 + half;
    const int total = N_ROWS + KCB;
    if (row >= total) return;
    const float* p = (row < N_ROWS) ? (lat + (size_t)row * DIM)
                                    : (emb + (size_t)(row - N_ROWS) * DIM);
    const float* q = p + 128 * b + j;
    float a0 = q[0];
    float r  = a0 * a0;
    for (int i = 1; i < 16; ++i) {
        float a = q[8 * i];
        float s = a * a;
        r = r + s;
    }
    r = r + __shfl_xor(r, 1);
    r = r + __shfl_xor(r, 2);
    r = r + __shfl_xor(r, 4);
    r = r + __shfl_xor(r, 8);
    r = r + __shfl_xor(r, 16);
    if (L == 0) {
        if (row < N_ROWS) row_sq[row] = r;
        else              emb_sq[row - N_ROWS] = r;
    }
}

// ---------------------------------------------------------------------------
// Kernel 2: fp32 -> fp8 e4m3 (OCP). emb pre-scaled by 2^13 (exact pow2).
// ---------------------------------------------------------------------------
__global__ void cvt_kernel(const float* __restrict__ lat,
                           const float* __restrict__ emb,
                           unsigned char* __restrict__ latq,
                           unsigned char* __restrict__ embq) {
    const size_t NL8 = (size_t)N_ROWS * DIM / 8;
    const size_t NE8 = (size_t)KCB * DIM / 8;
    size_t g = (size_t)blockIdx.x * 256 + threadIdx.x;
    const float* src; unsigned char* dst; size_t i; float sc;
    if (g < NL8)            { src = lat; dst = latq; i = g;       sc = 1.0f; }
    else if (g < NL8 + NE8) { src = emb; dst = embq; i = g - NL8; sc = 8192.0f; }
    else return;
    float4 v0 = ((const float4*)src)[2 * i];
    float4 v1 = ((const float4*)src)[2 * i + 1];
    int lo = __builtin_amdgcn_cvt_pk_fp8_f32(v0.x * sc, v0.y * sc, 0,  false);
    lo     = __builtin_amdgcn_cvt_pk_fp8_f32(v0.z * sc, v0.w * sc, lo, true);
    int hi = __builtin_amdgcn_cvt_pk_fp8_f32(v1.x * sc, v1.y * sc, 0,  false);
    hi     = __builtin_amdgcn_cvt_pk_fp8_f32(v1.z * sc, v1.w * sc, hi, true);
    ((int2*)dst)[i] = make_int2(lo, hi);
}

// ---------------------------------------------------------------------------
// Kernel 3: fp8 MFMA GEMM (transposed: D[code][latrow]). Block = 256 rows x
// (NITER x 128 codes), 256 threads. Per code-tile: per-(row,group) min +
// nibble-packed candidate bitmap (codes within MARGIN of group min), written
// as float4/ushort4 coalesced stores.
// ---------------------------------------------------------------------------
__device__ __forceinline__ void load16_to_lds(const void* g, void* l) {
    __builtin_amdgcn_global_load_lds(
        (const __attribute__((address_space(1))) unsigned int*)g,
        (__attribute__((address_space(3))) unsigned int*)l, 16, 0, 0);
}

template<int NG>
__global__ __launch_bounds__(256, 2) void gemm_kernel(
        const unsigned char* __restrict__ latq,
        const unsigned char* __restrict__ embq,
        const float* __restrict__ row_sq,
        const float* __restrict__ emb_sq,
        float* __restrict__ tilemin,
        void* __restrict__ bmp_raw) {
    __shared__ unsigned char Ac[4 * 128 * 16];   // codes [p][128][16B], 8 KB
    __shared__ unsigned char Br[4 * 256 * 16];   // rows  [p][256][16B], 16 KB

    const int tid   = threadIdx.x;
    const int w     = tid >> 6;
    const int lane  = tid & 63;
    const int q     = lane >> 4;
    const int m16   = lane & 15;
    const int row0  = blockIdx.x * 256;
    const int nbase = blockIdx.y * (NITER * 128);
    const int wc    = 64 * (w >> 1);
    const int rbase = 128 * (w & 1);

    float sxv[8];
#pragma unroll
    for (int c = 0; c < 8; ++c)
        sxv[c] = row_sq[row0 + rbase + 16 * c + m16];

    const float inv = 1.0f / 4096.0f;   // undo 2^13 emb scale on 2*dot

    for (int ni = 0; ni < NITER; ++ni) {
        const int n0 = nbase + ni * 128;
        float sev[4][4];
#pragma unroll
        for (int r = 0; r < 4; ++r)
#pragma unroll
            for (int reg = 0; reg < 4; ++reg)
                sev[r][reg] = emb_sq[n0 + wc + 16 * r + 4 * q + reg];

        f32x4 acc[4][8];
#pragma unroll
        for (int r = 0; r < 4; ++r)
#pragma unroll
            for (int c = 0; c < 8; ++c) acc[r][c] = (f32x4){0.f, 0.f, 0.f, 0.f};

        for (int k0 = 0; k0 < DIM; k0 += 64) {
#pragma unroll
            for (int i = 0; i < 6; ++i) {
                int cid = w * 6 + i;
                if (cid < 8) {
                    int p = cid >> 1, h = cid & 1;
                    const unsigned char* g = embq +
                        (size_t)(n0 + h * 64 + lane) * DIM + k0 + p * 16;
                    load16_to_lds(g, &Ac[(p * 128 + h * 64) * 16]);
                } else {
                    int c2 = cid - 8, p = c2 >> 2, h = c2 & 3;
                    const unsigned char* g = latq +
                        (size_t)(row0 + h * 64 + lane) * DIM + k0 + p * 16;
                    load16_to_lds(g, &Br[(p * 256 + h * 64) * 16]);
                }
            }
            __syncthreads();
#pragma unroll
            for (int kk = 0; kk < 2; ++kk) {
                long a[4], b[8];
                const int kg = kk * 4 + q;
                const int p  = kg >> 1, hf = (kg & 1) * 8;
#pragma unroll
                for (int r = 0; r < 4; ++r)
                    a[r] = *(const long*)&Ac[(p * 128 + wc + 16 * r + m16) * 16 + hf];
#pragma unroll
                for (int c = 0; c < 8; ++c)
                    b[c] = *(const long*)&Br[(p * 256 + rbase + 16 * c + m16) * 16 + hf];
#pragma unroll
                for (int r = 0; r < 4; ++r)
#pragma unroll
                    for (int c = 0; c < 8; ++c)
                        acc[r][c] = __builtin_amdgcn_mfma_f32_16x16x32_fp8_fp8(
                            a[r], b[c], acc[r][c], 0, 0, 0);
            }
            __syncthreads();
        }

        // epilogue: s = (sx+se) - 2^-12*dotq ; group min + nibble bitmap
        if (NG == 512) {
            unsigned short* bmp = (unsigned short*)bmp_raw;
#pragma unroll
            for (int c = 0; c < 8; ++c) {
                float    mins[4];
                unsigned bms[4];
#pragma unroll
                for (int r = 0; r < 4; ++r) {
                    float s0 = (sxv[c] + sev[r][0]) - acc[r][c][0] * inv;
                    float s1 = (sxv[c] + sev[r][1]) - acc[r][c][1] * inv;
                    float s2 = (sxv[c] + sev[r][2]) - acc[r][c][2] * inv;
                    float s3 = (sxv[c] + sev[r][3]) - acc[r][c][3] * inv;
                    float mn = fminf(fminf(s0, s1), fminf(s2, s3));
                    mn = fminf(mn, __shfl_xor(mn, 16));
                    mn = fminf(mn, __shfl_xor(mn, 32));
                    float t = mn + MARGIN;
                    unsigned nib = (s0 <= t ? 1u : 0u) | (s1 <= t ? 2u : 0u)
                                 | (s2 <= t ? 4u : 0u) | (s3 <= t ? 8u : 0u);
                    nib <<= (4 * q);
                    nib |= (unsigned)__shfl_xor((int)nib, 16);
                    nib |= (unsigned)__shfl_xor((int)nib, 32);
                    mins[r] = mn; bms[r] = nib;
                }
                if (lane < 16) {
                    int grow = row0 + rbase + 16 * c + m16;
                    int base = (n0 + wc) >> 4;
                    *(float4*)&tilemin[(size_t)grow * 512 + base] =
                        make_float4(mins[0], mins[1], mins[2], mins[3]);
                    ushort4 bv = { (unsigned short)bms[0], (unsigned short)bms[1],
                                   (unsigned short)bms[2], (unsigned short)bms[3] };
                    *(ushort4*)&bmp[(size_t)grow * 512 + base] = bv;
                }
            }
        } else {
            unsigned* bmp = (unsigned*)bmp_raw;
#pragma unroll
            for (int c = 0; c < 8; ++c) {
                float    mins[2];
                unsigned bms[2];
#pragma unroll
                for (int r2 = 0; r2 < 2; ++r2) {
                    float s[2][4];
#pragma unroll
                    for (int rr = 0; rr < 2; ++rr)
#pragma unroll
                        for (int reg = 0; reg < 4; ++reg)
                            s[rr][reg] = (sxv[c] + sev[2 * r2 + rr][reg])
                                         - acc[2 * r2 + rr][c][reg] * inv;
                    float mn = fminf(fminf(s[0][0], s[0][1]), fminf(s[0][2], s[0][3]));
#pragma unroll
                    for (int reg = 0; reg < 4; ++reg) mn = fminf(mn, s[1][reg]);
                    mn = fminf(mn, __shfl_xor(mn, 16));
                    mn = fminf(mn, __shfl_xor(mn, 32));
                    float t = mn + MARGIN;
                    unsigned n0b = (s[0][0] <= t ? 1u : 0u) | (s[0][1] <= t ? 2u : 0u)
                                 | (s[0][2] <= t ? 4u : 0u) | (s[0][3] <= t ? 8u : 0u);
                    unsigned n1b = (s[1][0] <= t ? 1u : 0u) | (s[1][1] <= t ? 2u : 0u)
                                 | (s[1][2] <= t ? 4u : 0u) | (s[1][3] <= t ? 8u : 0u);
                    unsigned bm = (n0b << (4 * q)) | (n1b << (16 + 4 * q));
                    bm |= (unsigned)__shfl_xor((int)bm, 16);
                    bm |= (unsigned)__shfl_xor((int)bm, 32);
                    mins[r2] = mn; bms[r2] = bm;
                }
                if (lane < 16) {
                    int grow = row0 + rbase + 16 * c + m16;
                    int base = (n0 + wc) >> 5;
                    *(float2*)&tilemin[(size_t)grow * 256 + base] =
                        make_float2(mins[0], mins[1]);
                    *(uint2*)&bmp[(size_t)grow * 256 + base] =
                        make_uint2(bms[0], bms[1]);
                }
            }
        }
    }
}

// ---------------------------------------------------------------------------
// Kernel 4 (fused): global min of group mins -> flagged groups -> candidate
// codes from bitmaps -> exact fp32 rescore (R1's bit-identical chain) ->
// outputs.
// ---------------------------------------------------------------------------
template<int NG>
__global__ __launch_bounds__(256) void argmin_out_kernel(
        const float* __restrict__ lat, const float* __restrict__ emb,
        const float* __restrict__ row_sq, const float* __restrict__ emb_sq,
        const float* __restrict__ tilemin, const void* __restrict__ bmp_raw,
        const int* __restrict__ gold,
        float* __restrict__ out, int* __restrict__ counter) {
    constexpr int GS = KCB / NG;
    constexpr int PL = NG / 64;
    __shared__ float xs[4][DIM];
    __shared__ int   s_cnt[4];
    __shared__ int   s_list[4][CAND_CAP];
    const int w    = threadIdx.x >> 6;
    const int lane = threadIdx.x & 63;
    const int row  = blockIdx.x * 4 + w;

    {
        const float4* xp = (const float4*)(lat + (size_t)row * DIM);
        ((float4*)xs[w])[lane]      = xp[lane];
        ((float4*)xs[w])[lane + 64] = xp[lane + 64];
    }
    const float sx = row_sq[row];
    const float* xw = xs[w];

    float tm[PL];
    {
        const float4* tb = (const float4*)(tilemin + (size_t)row * NG + lane * PL);
#pragma unroll
        for (int j4 = 0; j4 < PL / 4; ++j4) {
            float4 v = tb[j4];
            tm[4 * j4 + 0] = v.x; tm[4 * j4 + 1] = v.y;
            tm[4 * j4 + 2] = v.z; tm[4 * j4 + 3] = v.w;
        }
    }
    float m = tm[0];
#pragma unroll
    for (int j = 1; j < PL; ++j) m = fminf(m, tm[j]);
#pragma unroll
    for (int off = 1; off < 64; off <<= 1)
        m = fminf(m, __shfl_xor(m, off));
    const float thresh = m + MARGIN;

    if (lane == 0) s_cnt[w] = 0;
    __syncthreads();
#pragma unroll
    for (int j = 0; j < PL; ++j) {
        if (tm[j] <= thresh) {
            int g = lane * PL + j;
            unsigned bm;
            if (NG == 512)
                bm = ((const unsigned short*)bmp_raw)[(size_t)row * 512 + g];
            else
                bm = ((const unsigned*)bmp_raw)[(size_t)row * 256 + g];
            while (bm) {
                int b = __ffs(bm) - 1;
                bm &= bm - 1;
                int pos = atomicAdd(&s_cnt[w], 1);
                if (pos < CAND_CAP) s_list[w][pos] = g * GS + b;
            }
        }
    }
    __syncthreads();
    const int cnt = min(s_cnt[w], CAND_CAP);

    float bd = INFINITY;
    int   bi = 0x7fffffff;
    for (int base = 0; base < cnt; base += 64) {
        int ci = base + lane;
        float dvl = INFINITY;
        int   cl  = 0x7fffffff;
        if (ci < cnt) {
            int code = s_list[w][ci];
            const float* ep = emb + (size_t)code * DIM;
            float acc = 0.0f;
            for (int d = 0; d < DIM; d += 8) {
                float ev[8], xv[8];
#pragma unroll
                for (int t = 0; t < 8; ++t) { ev[t] = ep[d + t]; xv[t] = xw[d + t]; }
#pragma unroll
                for (int t = 0; t < 8; ++t) acc = fmaf(xv[t], ev[t], acc);
            }
            float a = sx + emb_sq[code];
            dvl = a - 2.0f * acc;
            cl  = code;
        }
        if (dvl < bd || (dvl == bd && cl < bi)) { bd = dvl; bi = cl; }
    }
#pragma unroll
    for (int off = 1; off < 64; off <<= 1) {
        float od = __shfl_xor(bd, off);
        int   oi = __shfl_xor(bi, off);
        if (od < bd || (od == bd && oi < bi)) { bd = od; bi = oi; }
    }
    const int idx = bi;

    const float4* e4 = (const float4*)(emb + (size_t)idx * DIM);
    float4*       q4 = (float4*)(out + (size_t)row * DIM);
    q4[lane]      = e4[lane];
    q4[lane + 64] = e4[lane + 64];

    float r = 0.0f;
    if (lane < 32) {
        const int b = lane >> 3, j = lane & 7;
        const float* ep = emb + (size_t)idx * DIM + b * 128 + j;
        const float* xp = xw + b * 128 + j;
        for (int i = 0; i < 16; ++i) {
            float dq = ep[8 * i] - xp[8 * i];
            float s  = dq * dq;
            r = (i == 0) ? s : (r + s);
        }
    }
    for (int mm = 1; mm <= 16; mm <<= 1) {
        float o = __shfl_xor(r, mm);
        r = r + o;
    }
    if (lane == 0) {
        float mean = r * (1.0f / 512.0f);
        float v    = mean + 0.25f * mean;
        out[(size_t)N_ROWS * DIM + row]          = v;
        out[(size_t)N_ROWS * DIM + N_ROWS + row] = (float)idx;
        if (gold[row] == idx) atomicAdd(counter, 1);
    }
}

__global__ void tail_kernel(const int* __restrict__ counter,
                            float* __restrict__ out) {
    if (threadIdx.x == 0 && blockIdx.x == 0) {
        const size_t off = (size_t)N_ROWS * DIM + 2 * (size_t)N_ROWS;
        out[off]     = (float)(*counter);
        out[off + 1] = (float)N_ROWS;
    }
}

// ---------------------------------------------------------------------------
// Fallback path (tiny ws): R1 fp32 dist + separate out kernel.
// ---------------------------------------------------------------------------
#define BM 64
#define BK 128
#define BD 32
__global__ __launch_bounds__(256) void dist_kernel(
        const float* __restrict__ lat, const float* __restrict__ emb,
        const float* __restrict__ row_sq, const float* __restrict__ emb_sq,
        int* __restrict__ enc) {
    __shared__ float xsh[BD][BM];
    __shared__ float esh[BD][BK];
    const int tid  = threadIdx.x;
    const int trow = tid >> 4;
    const int tcol = tid & 15;
    const int row0 = blockIdx.x * BM;
    float bd[4]; int bi[4];
    for (int i = 0; i < 4; ++i) { bd[i] = INFINITY; bi[i] = 0; }
    float sx[4];
    for (int i = 0; i < 4; ++i) sx[i] = row_sq[row0 + 4 * trow + i];
    for (int kt = 0; kt < KCB; kt += BK) {
        float acc[4][8] = {};
        for (int d0 = 0; d0 < DIM; d0 += BD) {
            for (int f = tid; f < BM * BD / 4; f += 256) {
                int r = f >> 3, c4 = f & 7;
                float4 v = *(const float4*)(lat + (size_t)(row0 + r) * DIM + d0 + 4 * c4);
                xsh[4 * c4 + 0][r] = v.x; xsh[4 * c4 + 1][r] = v.y;
                xsh[4 * c4 + 2][r] = v.z; xsh[4 * c4 + 3][r] = v.w;
            }
            for (int f = tid; f < BK * BD / 4; f += 256) {
                int r = f >> 3, c4 = f & 7;
                float4 v = *(const float4*)(emb + (size_t)(kt + r) * DIM + d0 + 4 * c4);
                esh[4 * c4 + 0][r] = v.x; esh[4 * c4 + 1][r] = v.y;
                esh[4 * c4 + 2][r] = v.z; esh[4 * c4 + 3][r] = v.w;
            }
            __syncthreads();
            for (int dd = 0; dd < BD; ++dd) {
                float4 xv  = *(const float4*)&xsh[dd][4 * trow];
                float4 ev0 = *(const float4*)&esh[dd][8 * tcol];
                float4 ev1 = *(const float4*)&esh[dd][8 * tcol + 4];
                float xr[4] = { xv.x, xv.y, xv.z, xv.w };
                float ec[8] = { ev0.x, ev0.y, ev0.z, ev0.w, ev1.x, ev1.y, ev1.z, ev1.w };
                for (int r = 0; r < 4; ++r)
                    for (int c = 0; c < 8; ++c)
                        acc[r][c] = fmaf(xr[r], ec[c], acc[r][c]);
            }
            __syncthreads();
        }
        for (int c = 0; c < 8; ++c) {
            int   code = kt + 8 * tcol + c;
            float se   = emb_sq[code];
            for (int r = 0; r < 4; ++r) {
                float a  = sx[r] + se;
                float dv = a - 2.0f * acc[r][c];
                if (dv < bd[r]) { bd[r] = dv; bi[r] = code; }
            }
        }
    }
    for (int off = 1; off < 16; off <<= 1) {
        for (int r = 0; r < 4; ++r) {
            float od = __shfl_xor(bd[r], off);
            int   oi = __shfl_xor(bi[r], off);
            if (od < bd[r] || (od == bd[r] && oi < bi[r])) { bd[r] = od; bi[r] = oi; }
        }
    }
    if (tcol == 0)
        for (int r = 0; r < 4; ++r)
            enc[row0 + 4 * trow + r] = bi[r];
}

__global__ void out_kernel(const float* __restrict__ lat,
                           const float* __restrict__ emb,
                           const int* __restrict__ gold,
                           const int* __restrict__ enc,
                           float* __restrict__ out,
                           int* __restrict__ counter) {
#pragma clang fp contract(off)
    const int gid  = blockIdx.x * blockDim.x + threadIdx.x;
    const int row  = gid >> 6;
    const int lane = threadIdx.x & 63;
    if (row >= N_ROWS) return;
    const int idx = enc[row];
    const float4* e4 = (const float4*)(emb + (size_t)idx * DIM);
    float4*       q4 = (float4*)(out + (size_t)row * DIM);
    q4[lane]      = e4[lane];
    q4[lane + 64] = e4[lane + 64];
    float r = 0.0f;
    if (lane < 32) {
        const int b = lane >> 3, j = lane & 7;
        const float* ep = emb + (size_t)idx * DIM + b * 128 + j;
        const float* xp = lat + (size_t)row * DIM + b * 128 + j;
        for (int i = 0; i < 16; ++i) {
            float dq = ep[8 * i] - xp[8 * i];
            float s  = dq * dq;
            r = (i == 0) ? s : (r + s);
        }
    }
    for (int m = 1; m <= 16; m <<= 1) {
        float o = __shfl_xor(r, m);
        r = r + o;
    }
    if (lane == 0) {
        float mean = r * (1.0f / 512.0f);
        float v    = mean + 0.25f * mean;
        out[(size_t)N_ROWS * DIM + row]          = v;
        out[(size_t)N_ROWS * DIM + N_ROWS + row] = (float)idx;
        if (gold[row] == idx) atomicAdd(counter, 1);
    }
}

// ---------------------------------------------------------------------------
extern "C" void kernel_launch(void* const* d_in, const int* in_sizes, int n_in,
                              void* d_out, int out_size, void* d_ws, size_t ws_size,
                              hipStream_t stream) {
    (void)in_sizes; (void)n_in; (void)out_size;
    const int*   gold = (const int*)d_in[0];
    const float* lat  = (const float*)d_in[1];
    const float* emb  = (const float*)d_in[3];
    float* out = (float*)d_out;

    const size_t SZ_LATQ  = (size_t)N_ROWS * DIM;
    const size_t SZ_EMBQ  = (size_t)KCB * DIM;
    const size_t SZ_TM512 = (size_t)N_ROWS * 512 * 4;
    const size_t SZ_BM512 = (size_t)N_ROWS * 512 * 2;
    const size_t SZ_TM256 = (size_t)N_ROWS * 256 * 4;
    const size_t SZ_BM256 = (size_t)N_ROWS * 256 * 4;
    const size_t SZ_SMALL = (size_t)N_ROWS * 4 + (size_t)KCB * 4 + 256;
    const size_t NEED512 = SZ_LATQ + SZ_EMBQ + SZ_TM512 + SZ_BM512 + SZ_SMALL;
    const size_t NEED256 = SZ_LATQ + SZ_EMBQ + SZ_TM256 + SZ_BM256 + SZ_SMALL;

    if (ws_size >= NEED256) {
        const bool g16 = (ws_size >= NEED512);
        const size_t SZ_TM = g16 ? SZ_TM512 : SZ_TM256;
        const size_t SZ_BM = g16 ? SZ_BM512 : SZ_BM256;
        unsigned char* w8 = (unsigned char*)d_ws;
        unsigned char* latq    = w8;
        unsigned char* embq    = w8 + SZ_LATQ;
        float*         tilemin = (float*)(w8 + SZ_LATQ + SZ_EMBQ);
        void*          bmp     = (void*)(w8 + SZ_LATQ + SZ_EMBQ + SZ_TM);
        float*         row_sq  = (float*)(w8 + SZ_LATQ + SZ_EMBQ + SZ_TM + SZ_BM);
        float*         emb_sq  = row_sq + N_ROWS;
        int*           counter = (int*)(emb_sq + KCB);

        hipMemsetAsync(counter, 0, sizeof(int), stream);
        sq_kernel<<<(N_ROWS + KCB) / 8, 256, 0, stream>>>(lat, emb, row_sq, emb_sq);
        cvt_kernel<<<(N_ROWS + KCB) * (DIM / 8) / 256, 256, 0, stream>>>(lat, emb, latq, embq);
        dim3 ggrid(N_ROWS / 256, KCB / (NITER * 128));
        if (g16) {
            gemm_kernel<512><<<ggrid, 256, 0, stream>>>(latq, embq, row_sq, emb_sq, tilemin, bmp);
            argmin_out_kernel<512><<<N_ROWS / 4, 256, 0, stream>>>(
                lat, emb, row_sq, emb_sq, tilemin, bmp, gold, out, counter);
        } else {
            gemm_kernel<256><<<ggrid, 256, 0, stream>>>(latq, embq, row_sq, emb_sq, tilemin, bmp);
            argmin_out_kernel<256><<<N_ROWS / 4, 256, 0, stream>>>(
                lat, emb, row_sq, emb_sq, tilemin, bmp, gold, out, counter);
        }
        tail_kernel<<<1, 64, 0, stream>>>(counter, out);
    } else {
        float* row_sq  = (float*)d_ws;
        float* emb_sq  = row_sq + N_ROWS;
        int*   enc     = (int*)(emb_sq + KCB);
        int*   counter = enc + N_ROWS;
        hipMemsetAsync(counter, 0, sizeof(int), stream);
        sq_kernel<<<(N_ROWS + KCB) / 8, 256, 0, stream>>>(lat, emb, row_sq, emb_sq);
        dist_kernel<<<N_ROWS / BM, 256, 0, stream>>>(lat, emb, row_sq, emb_sq, enc);
        out_kernel<<<N_ROWS / 4, 256, 0, stream>>>(lat, emb, gold, enc, out, counter);
        tail_kernel<<<1, 64, 0, stream>>>(counter, out);
    }
}